// Round 4
// baseline (1000.217 us; speedup 1.0000x reference)
//
#include <hip/hip_runtime.h>

typedef short bf16x8 __attribute__((ext_vector_type(8)));
typedef float f32x4 __attribute__((ext_vector_type(4)));

#define MFMA16(a, b, c) __builtin_amdgcn_mfma_f32_16x16x32_bf16((a), (b), (c), 0, 0, 0)

#define SEQ 4096
#define CD 512

#define LGKM0 asm volatile("s_waitcnt lgkmcnt(0)" ::: "memory")
#define VM0   asm volatile("s_waitcnt vmcnt(0)" ::: "memory")

__device__ __forceinline__ unsigned short f2bf(float f) {
  unsigned u = __builtin_bit_cast(unsigned, f);
  u = u + 0x7FFFu + ((u >> 16) & 1u);
  return (unsigned short)(u >> 16);
}

__device__ __forceinline__ void gload_lds16(const void* g, void* l) {
  __builtin_amdgcn_global_load_lds(
      (const __attribute__((address_space(1))) void*)g,
      (__attribute__((address_space(3))) void*)l, 16, 0, 0);
}

// ---------------- weight convert (fp32 -> bf16, fold softmax scale into Wq/bq) ----------------
__global__ __launch_bounds__(256) void convert_w(
    const float* __restrict__ Wq, const float* __restrict__ Wk,
    const float* __restrict__ Wv, const float* __restrict__ Wo,
    const float* __restrict__ bq, const float* __restrict__ bk,
    const float* __restrict__ bv, const float* __restrict__ bo,
    unsigned short* __restrict__ W4, float* __restrict__ b4) {
  int i = blockIdx.x * 256 + threadIdx.x;            // 4*512*512 total
  int p = i >> 18, idx = i & 262143;
  const float sc = 1.4426950408889634f * 0.04419417382415922f;  // log2(e) * 512^-0.5
  const float* W = (p == 0) ? Wq : (p == 1) ? Wk : (p == 2) ? Wv : Wo;
  float v = W[idx] * ((p == 0) ? sc : 1.0f);
  W4[i] = f2bf(v);
  if (idx < 512) {
    const float* bb = (p == 0) ? bq : (p == 1) ? bk : (p == 2) ? bv : bo;
    b4[(p << 9) + idx] = bb[idx] * ((p == 0) ? sc : 1.0f);
  }
}

// ---------------- transpose q: fp32 [b][c][s] -> bf16 qT [b][s][c] ----------------
__global__ __launch_bounds__(256) void transpose_q(
    const float* __restrict__ q, unsigned short* __restrict__ qT) {
  __shared__ float tile[32][33];
  const int b = blockIdx.z, c0 = blockIdx.y * 32, s0 = blockIdx.x * 32;
  const int tx = threadIdx.x & 31, ty = threadIdx.x >> 5;
  #pragma unroll
  for (int i = 0; i < 4; i++) {
    int c = ty + i * 8;
    tile[c][tx] = q[((size_t)b * CD + c0 + c) * SEQ + s0 + tx];
  }
  __syncthreads();
  #pragma unroll
  for (int i = 0; i < 4; i++) {
    int s = ty + i * 8;
    qT[((size_t)b * SEQ + s0 + s) * CD + c0 + tx] = f2bf(tile[tx][s]);
  }
}

// ---------------- shared BT-GEMM core: 128x128 tile, BK=64, 4 waves ----------------
__device__ __forceinline__ void gemm_core(
    const unsigned short* __restrict__ Ap, const unsigned short* __restrict__ Bp,
    unsigned short* As, unsigned short* Bs, f32x4 acc[4][4]) {
  const int t = threadIdx.x;
  const int wid = t >> 6, lane = t & 63;
  const int l15 = lane & 15, l4 = lane >> 4;
  const int wr = wid >> 1, wc = wid & 1;
  for (int k0 = 0; k0 < 512; k0 += 64) {
    #pragma unroll
    for (int j = 0; j < 4; j++) {
      int slot = j * 256 + t;
      int row = slot >> 3, kc = slot & 7;
      int kcs = kc ^ (row & 7);
      gload_lds16(Ap + (size_t)row * 512 + k0 + kcs * 8, As + (j * 256 + wid * 64) * 8);
      gload_lds16(Bp + (size_t)row * 512 + k0 + kcs * 8, Bs + (j * 256 + wid * 64) * 8);
    }
    __syncthreads();
    #pragma unroll
    for (int ks = 0; ks < 2; ks++) {
      bf16x8 af[4], bf[4];
      #pragma unroll
      for (int i = 0; i < 4; i++) {
        int ra = wr * 64 + i * 16 + l15;
        af[i] = *(const bf16x8*)(As + ra * 64 + (((ks << 2) | l4) ^ (ra & 7)) * 8);
        int rb = wc * 64 + i * 16 + l15;
        bf[i] = *(const bf16x8*)(Bs + rb * 64 + (((ks << 2) | l4) ^ (rb & 7)) * 8);
      }
      #pragma unroll
      for (int i = 0; i < 4; i++)
        #pragma unroll
        for (int j = 0; j < 4; j++)
          acc[i][j] = MFMA16(af[i], bf[j], acc[i][j]);
    }
    __syncthreads();
  }
}

// ---------------- QKV projection: z = 0(Q),1(K),2(V transposed) ----------------
__global__ __launch_bounds__(256) void gemm_proj(
    const unsigned short* __restrict__ qT, const unsigned short* __restrict__ W4,
    const float* __restrict__ b4,
    unsigned short* __restrict__ Qf, unsigned short* __restrict__ Kf,
    unsigned short* __restrict__ VfT) {
  __shared__ unsigned short As[128 * 64], Bs[128 * 64];
  const int p = blockIdx.z;
  const int n0 = blockIdx.x * 128, m0 = blockIdx.y * 128;
  f32x4 acc[4][4];
  #pragma unroll
  for (int i = 0; i < 4; i++)
    #pragma unroll
    for (int j = 0; j < 4; j++) acc[i][j] = (f32x4){0.f, 0.f, 0.f, 0.f};
  gemm_core(qT + (size_t)m0 * 512, W4 + ((size_t)p * 512 + n0) * 512, As, Bs, acc);

  const int t = threadIdx.x;
  const int wid = t >> 6, lane = t & 63;
  const int l15 = lane & 15, l4 = lane >> 4;
  const int wr = wid >> 1, wc = wid & 1;

  if (p < 2) {
    unsigned short* out = (p == 0) ? Qf : Kf;
    #pragma unroll
    for (int j = 0; j < 4; j++) {
      int n = n0 + wc * 64 + j * 16 + l15;
      float bias = b4[p * 512 + n];
      #pragma unroll
      for (int i = 0; i < 4; i++) {
        int m = m0 + wr * 64 + i * 16 + l4 * 4;
        #pragma unroll
        for (int r = 0; r < 4; r++)
          out[(size_t)(m + r) * 512 + n] = f2bf(acc[i][j][r] + bias);
      }
    }
  } else {
    int bb = m0 >> 12, sb = m0 & 4095;
    #pragma unroll
    for (int j = 0; j < 4; j++) {
      int n = n0 + wc * 64 + j * 16 + l15;
      float bias = b4[2 * 512 + n];
      #pragma unroll
      for (int i = 0; i < 4; i++) {
        int s = sb + wr * 64 + i * 16 + l4 * 4;
        ushort4 v;
        v.x = f2bf(acc[i][j][0] + bias);
        v.y = f2bf(acc[i][j][1] + bias);
        v.z = f2bf(acc[i][j][2] + bias);
        v.w = f2bf(acc[i][j][3] + bias);
        *(ushort4*)&VfT[((size_t)bb * CD + n) * SEQ + s] = v;
      }
    }
  }
}

// ---------------- flash attention: QBLK=32, KVBLK=64, 8 waves, fixed-max softmax ----------------
// 8 waves = 4 cw (c/kv strips) x 2 qw (16-q strips). One barrier per tile, double-buffered P.
// Fixed max m=0 (|S|<~2 with folded scale): no max pass, no rescale, no stats exchange.
#define LOADK(B, base, c)                                        \
  B##_0 = *(const bf16x8*)((base) + ((c) * 4 + 0) * 32);         \
  B##_1 = *(const bf16x8*)((base) + ((c) * 4 + 1) * 32);         \
  B##_2 = *(const bf16x8*)((base) + ((c) * 4 + 2) * 32);         \
  B##_3 = *(const bf16x8*)((base) + ((c) * 4 + 3) * 32);

#define QVL(ck) (*(const bf16x8*)((const char*)Qs + qq * 1024 + (((ck) * 64 + l4 * 16) ^ qswz)))

#define QKC(B, c, S)                            \
  S = MFMA16(B##_0, QVL((c) * 4 + 0), S);       \
  S = MFMA16(B##_1, QVL((c) * 4 + 1), S);       \
  S = MFMA16(B##_2, QVL((c) * 4 + 2), S);       \
  S = MFMA16(B##_3, QVL((c) * 4 + 3), S);

#define LOADV(B, h, kvs)                                                            \
  B##_0 = *(const bf16x8*)(vt + (size_t)((h) * 4 + 0) * 16 * SEQ + (kvs) * 32);     \
  B##_1 = *(const bf16x8*)(vt + (size_t)((h) * 4 + 1) * 16 * SEQ + (kvs) * 32);     \
  B##_2 = *(const bf16x8*)(vt + (size_t)((h) * 4 + 2) * 16 * SEQ + (kvs) * 32);     \
  B##_3 = *(const bf16x8*)(vt + (size_t)((h) * 4 + 3) * 16 * SEQ + (kvs) * 32);

#define PVC(B, h, PB)                                    \
  acc[(h) * 4 + 0] = MFMA16(B##_0, PB, acc[(h) * 4 + 0]); \
  acc[(h) * 4 + 1] = MFMA16(B##_1, PB, acc[(h) * 4 + 1]); \
  acc[(h) * 4 + 2] = MFMA16(B##_2, PB, acc[(h) * 4 + 2]); \
  acc[(h) * 4 + 3] = MFMA16(B##_3, PB, acc[(h) * 4 + 3]);

__global__ __launch_bounds__(512, 4) void flash_attn(
    const unsigned short* __restrict__ Qf, const unsigned short* __restrict__ Kf,
    const unsigned short* __restrict__ VfT, unsigned short* __restrict__ Ao) {
  __shared__ unsigned short Qs[32 * 512];   // 32KB, chunk-swizzled
  __shared__ unsigned short Ps[2][32 * 64]; // 2x4KB double buffer, [q][kv] swizzled
  __shared__ float ssum[2][4][16];

  const int t = threadIdx.x;
  const int wid = t >> 6, lane = t & 63;
  const int cw = wid & 3, qw = wid >> 2;
  const int l15 = lane & 15, l4 = lane >> 4;

  // XCD-batch affinity: xcd = id&7 owns batch xcd>>1; 64 q-tiles per XCD.
  const int id = blockIdx.x;
  const int xcd = id & 7;
  const int b = xcd >> 1;
  const int q0 = ((id >> 3) + ((xcd & 1) << 6)) * 32;

  {  // stage Q tile (32 x 512) into LDS, source-chunk swizzled
    const unsigned short* qb = Qf + ((size_t)b * SEQ + q0) * CD;
    #pragma unroll
    for (int i = 0; i < 4; i++) {
      int slot = i * 512 + t;
      int row = slot >> 6, kc = slot & 63;
      int kcs = kc ^ (row & 7);
      gload_lds16(qb + (size_t)row * CD + kcs * 8, Qs + (size_t)(i * 512 + wid * 64) * 8);
    }
  }

  const unsigned short* kbase = Kf + ((size_t)b * SEQ + cw * 16 + l15) * CD + l4 * 8;
  const unsigned short* vbase = VfT + ((size_t)b * CD + cw * 128 + l15) * SEQ + l4 * 8;

  const int qq = qw * 16 + l15;
  const int qswz = (qq & 7) << 4;

  f32x4 acc[8];
  #pragma unroll
  for (int i = 0; i < 8; i++) acc[i] = (f32x4){0.f, 0.f, 0.f, 0.f};
  f32x4 l_acc = (f32x4){0.f, 0.f, 0.f, 0.f};

  bf16x8 kc0_0, kc0_1, kc0_2, kc0_3, kc1_0, kc1_1, kc1_2, kc1_3;
  bf16x8 vb0_0, vb0_1, vb0_2, vb0_3, vb1_0, vb1_1, vb1_2, vb1_3;

  LOADK(kc0, kbase, 0);   // tile 0 chunk 0
  VM0;                    // Q staged + kc0 in regs
  __builtin_amdgcn_s_barrier();

  for (int kv0 = 0; kv0 < SEQ; kv0 += 64) {
    const unsigned short* kt = kbase + (size_t)kv0 * CD;
    const unsigned short* ktn = kbase + (size_t)((kv0 + 64 < SEQ) ? kv0 + 64 : kv0) * CD;
    const unsigned short* vt = vbase + kv0;
    unsigned short* Pb = &Ps[(kv0 >> 6) & 1][0];

    // ---- QK^T: S^T[16kv strip][16q strip], K streamed 2-stage ----
    f32x4 sf0 = (f32x4){0.f, 0.f, 0.f, 0.f}, sf1 = (f32x4){0.f, 0.f, 0.f, 0.f};
    __builtin_amdgcn_s_setprio(1);
    LOADK(kc1, kt, 1);
    QKC(kc0, 0, sf0);
    LOADK(kc0, kt, 2);
    QKC(kc1, 1, sf1);
    LOADK(kc1, kt, 3);
    QKC(kc0, 2, sf0);
    QKC(kc1, 3, sf1);
    __builtin_amdgcn_s_setprio(0);

    // ---- P = exp2(S) (fixed max 0), accumulate l, write P bf16 to LDS ----
    {
      f32x4 s = sf0 + sf1;
      float p0 = __builtin_amdgcn_exp2f(s[0]);
      float p1 = __builtin_amdgcn_exp2f(s[1]);
      float p2 = __builtin_amdgcn_exp2f(s[2]);
      float p3 = __builtin_amdgcn_exp2f(s[3]);
      l_acc[0] += p0; l_acc[1] += p1; l_acc[2] += p2; l_acc[3] += p3;
      ushort4 pk;
      pk.x = f2bf(p0); pk.y = f2bf(p1); pk.z = f2bf(p2); pk.w = f2bf(p3);
      int off = qq * 128 + ((cw * 32 + l4 * 8) ^ qswz);
      *(ushort4*)((char*)Pb + off) = pk;
    }

    // ---- issue V loads + next-tile K chunk0 before the barrier ----
    LOADV(vb0, 0, 0);
    LOADV(vb1, 1, 0);
    LOADK(kc0, ktn, 0);

    LGKM0;                             // P writes visible (no vmcnt drain)
    __builtin_amdgcn_s_barrier();

    // ---- PV: O^T[128c strip][16q strip] += V x P^T ----
    bf16x8 pb0 = *(const bf16x8*)((const char*)Pb + qq * 128 + ((0 * 64 + l4 * 16) ^ qswz));
    __builtin_amdgcn_s_setprio(1);
    PVC(vb0, 0, pb0);
    LOADV(vb0, 0, 1);
    PVC(vb1, 1, pb0);
    __builtin_amdgcn_s_setprio(0);
    bf16x8 pb1 = *(const bf16x8*)((const char*)Pb + qq * 128 + ((1 * 64 + l4 * 16) ^ qswz));
    LOADV(vb1, 1, 1);
    __builtin_amdgcn_s_setprio(1);
    PVC(vb0, 0, pb1);
    PVC(vb1, 1, pb1);
    __builtin_amdgcn_s_setprio(0);
  }

  // ---- epilogue: reduce l across lanes and cw waves, normalize, store ----
  float strip = (l_acc[0] + l_acc[1]) + (l_acc[2] + l_acc[3]);
  strip += __shfl_xor(strip, 16, 64);
  strip += __shfl_xor(strip, 32, 64);
  __syncthreads();                     // all PV reads of Ps done (reuse-safe) before stats
  if (lane < 16) ssum[qw][cw][l15] = strip;
  __syncthreads();
  float total = (ssum[qw][0][l15] + ssum[qw][1][l15]) + (ssum[qw][2][l15] + ssum[qw][3][l15]);
  float inv = 1.0f / total;

  #pragma unroll
  for (int i = 0; i < 8; i++) {
    int c0 = cw * 128 + i * 16 + l4 * 4;
    ushort4 o4;
    o4.x = f2bf(acc[i][0] * inv); o4.y = f2bf(acc[i][1] * inv);
    o4.z = f2bf(acc[i][2] * inv); o4.w = f2bf(acc[i][3] * inv);
    *(ushort4*)&Ao[((size_t)b * SEQ + q0 + qq) * CD + c0] = o4;
  }
}

// ---------------- output projection: out[b][o][s] fp32 ----------------
__global__ __launch_bounds__(256) void gemm_out(
    const unsigned short* __restrict__ W4, const float* __restrict__ b4,
    const unsigned short* __restrict__ Ao, float* __restrict__ out) {
  __shared__ unsigned short As[128 * 64], Bs[128 * 64];
  const int b = blockIdx.z;
  const int n0 = blockIdx.x * 128, m0 = blockIdx.y * 128;
  f32x4 acc[4][4];
  #pragma unroll
  for (int i = 0; i < 4; i++)
    #pragma unroll
    for (int j = 0; j < 4; j++) acc[i][j] = (f32x4){0.f, 0.f, 0.f, 0.f};
  gemm_core(W4 + ((size_t)3 * 512 + m0) * 512, Ao + ((size_t)b * SEQ + n0) * 512, As, Bs, acc);

  const int t = threadIdx.x;
  const int wid = t >> 6, lane = t & 63;
  const int l15 = lane & 15, l4 = lane >> 4;
  const int wr = wid >> 1, wc = wid & 1;
  #pragma unroll
  for (int i = 0; i < 4; i++) {
    int m = m0 + wr * 64 + i * 16 + l4 * 4;
    #pragma unroll
    for (int j = 0; j < 4; j++) {
      int n = n0 + wc * 64 + j * 16 + l15;
      #pragma unroll
      for (int r = 0; r < 4; r++)
        out[((size_t)b * CD + m + r) * SEQ + n] = acc[i][j][r] + b4[3 * 512 + m + r];
    }
  }
}

extern "C" void kernel_launch(void* const* d_in, const int* in_sizes, int n_in,
                              void* d_out, int out_size, void* d_ws, size_t ws_size,
                              hipStream_t stream) {
  (void)in_sizes; (void)n_in; (void)out_size; (void)ws_size;
  const float* q  = (const float*)d_in[0];
  const float* Wq = (const float*)d_in[1];
  const float* bq = (const float*)d_in[2];
  const float* Wk = (const float*)d_in[3];
  const float* bk = (const float*)d_in[4];
  const float* Wv = (const float*)d_in[5];
  const float* bv = (const float*)d_in[6];
  const float* Wo = (const float*)d_in[7];
  const float* bo = (const float*)d_in[8];
  float* out = (float*)d_out;

  char* ws = (char*)d_ws;
  unsigned short* qT  = (unsigned short*)(ws);                     // 16MB (reused as Ao)
  unsigned short* Qf  = (unsigned short*)(ws + ((size_t)16 << 20));
  unsigned short* Kf  = (unsigned short*)(ws + ((size_t)32 << 20));
  unsigned short* VfT = (unsigned short*)(ws + ((size_t)48 << 20));
  unsigned short* W4  = (unsigned short*)(ws + ((size_t)64 << 20)); // 2MB
  float* b4           = (float*)(ws + ((size_t)66 << 20));          // 8KB
  unsigned short* Ao = qT;

  convert_w<<<4096, 256, 0, stream>>>(Wq, Wk, Wv, Wo, bq, bk, bv, bo, W4, b4);
  transpose_q<<<dim3(128, 16, 4), 256, 0, stream>>>(q, qT);
  gemm_proj<<<dim3(4, 128, 3), 256, 0, stream>>>(qT, W4, b4, Qf, Kf, VfT);
  flash_attn<<<512, 512, 0, stream>>>(Qf, Kf, VfT, Ao);
  gemm_out<<<dim3(32, 4, 4), 256, 0, stream>>>(W4, b4, Ao, out);
}

// Round 5
// 463.290 us; speedup vs baseline: 2.1589x; 2.1589x over previous
//
#include <hip/hip_runtime.h>

typedef short bf16x8 __attribute__((ext_vector_type(8)));
typedef float f32x4 __attribute__((ext_vector_type(4)));

#define MFMA16(a, b, c) __builtin_amdgcn_mfma_f32_16x16x32_bf16((a), (b), (c), 0, 0, 0)

#define SEQ 4096
#define CD 512

#define LGKM0 asm volatile("s_waitcnt lgkmcnt(0)" ::: "memory")
#define VM0   asm volatile("s_waitcnt vmcnt(0)" ::: "memory")

__device__ __forceinline__ unsigned short f2bf(float f) {
  unsigned u = __builtin_bit_cast(unsigned, f);
  u = u + 0x7FFFu + ((u >> 16) & 1u);
  return (unsigned short)(u >> 16);
}

__device__ __forceinline__ void gload_lds16(const void* g, void* l) {
  __builtin_amdgcn_global_load_lds(
      (const __attribute__((address_space(1))) void*)g,
      (__attribute__((address_space(3))) void*)l, 16, 0, 0);
}

// ---------------- weight convert (fp32 -> bf16, fold softmax scale into Wq/bq) ----------------
__global__ __launch_bounds__(256) void convert_w(
    const float* __restrict__ Wq, const float* __restrict__ Wk,
    const float* __restrict__ Wv, const float* __restrict__ Wo,
    const float* __restrict__ bq, const float* __restrict__ bk,
    const float* __restrict__ bv, const float* __restrict__ bo,
    unsigned short* __restrict__ W4, float* __restrict__ b4) {
  int i = blockIdx.x * 256 + threadIdx.x;            // 4*512*512 total
  int p = i >> 18, idx = i & 262143;
  const float sc = 1.4426950408889634f * 0.04419417382415922f;  // log2(e) * 512^-0.5
  const float* W = (p == 0) ? Wq : (p == 1) ? Wk : (p == 2) ? Wv : Wo;
  float v = W[idx] * ((p == 0) ? sc : 1.0f);
  W4[i] = f2bf(v);
  if (idx < 512) {
    const float* bb = (p == 0) ? bq : (p == 1) ? bk : (p == 2) ? bv : bo;
    b4[(p << 9) + idx] = bb[idx] * ((p == 0) ? sc : 1.0f);
  }
}

// ---------------- transpose q: fp32 [b][c][s] -> bf16 qT [b][s][c] ----------------
__global__ __launch_bounds__(256) void transpose_q(
    const float* __restrict__ q, unsigned short* __restrict__ qT) {
  __shared__ float tile[32][33];
  const int b = blockIdx.z, c0 = blockIdx.y * 32, s0 = blockIdx.x * 32;
  const int tx = threadIdx.x & 31, ty = threadIdx.x >> 5;
  #pragma unroll
  for (int i = 0; i < 4; i++) {
    int c = ty + i * 8;
    tile[c][tx] = q[((size_t)b * CD + c0 + c) * SEQ + s0 + tx];
  }
  __syncthreads();
  #pragma unroll
  for (int i = 0; i < 4; i++) {
    int s = ty + i * 8;
    qT[((size_t)b * SEQ + s0 + s) * CD + c0 + tx] = f2bf(tile[tx][s]);
  }
}

// ---------------- shared BT-GEMM core: 128x128 tile, BK=64, 4 waves ----------------
__device__ __forceinline__ void gemm_core(
    const unsigned short* __restrict__ Ap, const unsigned short* __restrict__ Bp,
    unsigned short* As, unsigned short* Bs, f32x4 acc[4][4]) {
  const int t = threadIdx.x;
  const int wid = t >> 6, lane = t & 63;
  const int l15 = lane & 15, l4 = lane >> 4;
  const int wr = wid >> 1, wc = wid & 1;
  for (int k0 = 0; k0 < 512; k0 += 64) {
    #pragma unroll
    for (int j = 0; j < 4; j++) {
      int slot = j * 256 + t;
      int row = slot >> 3, kc = slot & 7;
      int kcs = kc ^ (row & 7);
      gload_lds16(Ap + (size_t)row * 512 + k0 + kcs * 8, As + (j * 256 + wid * 64) * 8);
      gload_lds16(Bp + (size_t)row * 512 + k0 + kcs * 8, Bs + (j * 256 + wid * 64) * 8);
    }
    __syncthreads();
    #pragma unroll
    for (int ks = 0; ks < 2; ks++) {
      bf16x8 af[4], bf[4];
      #pragma unroll
      for (int i = 0; i < 4; i++) {
        int ra = wr * 64 + i * 16 + l15;
        af[i] = *(const bf16x8*)(As + ra * 64 + (((ks << 2) | l4) ^ (ra & 7)) * 8);
        int rb = wc * 64 + i * 16 + l15;
        bf[i] = *(const bf16x8*)(Bs + rb * 64 + (((ks << 2) | l4) ^ (rb & 7)) * 8);
      }
      #pragma unroll
      for (int i = 0; i < 4; i++)
        #pragma unroll
        for (int j = 0; j < 4; j++)
          acc[i][j] = MFMA16(af[i], bf[j], acc[i][j]);
    }
    __syncthreads();
  }
}

// ---------------- QKV projection: z = 0(Q),1(K),2(V transposed) ----------------
__global__ __launch_bounds__(256) void gemm_proj(
    const unsigned short* __restrict__ qT, const unsigned short* __restrict__ W4,
    const float* __restrict__ b4,
    unsigned short* __restrict__ Qf, unsigned short* __restrict__ Kf,
    unsigned short* __restrict__ VfT) {
  __shared__ unsigned short As[128 * 64], Bs[128 * 64];
  const int p = blockIdx.z;
  const int n0 = blockIdx.x * 128, m0 = blockIdx.y * 128;
  f32x4 acc[4][4];
  #pragma unroll
  for (int i = 0; i < 4; i++)
    #pragma unroll
    for (int j = 0; j < 4; j++) acc[i][j] = (f32x4){0.f, 0.f, 0.f, 0.f};
  gemm_core(qT + (size_t)m0 * 512, W4 + ((size_t)p * 512 + n0) * 512, As, Bs, acc);

  const int t = threadIdx.x;
  const int wid = t >> 6, lane = t & 63;
  const int l15 = lane & 15, l4 = lane >> 4;
  const int wr = wid >> 1, wc = wid & 1;

  if (p < 2) {
    unsigned short* out = (p == 0) ? Qf : Kf;
    #pragma unroll
    for (int j = 0; j < 4; j++) {
      int n = n0 + wc * 64 + j * 16 + l15;
      float bias = b4[p * 512 + n];
      #pragma unroll
      for (int i = 0; i < 4; i++) {
        int m = m0 + wr * 64 + i * 16 + l4 * 4;
        #pragma unroll
        for (int r = 0; r < 4; r++)
          out[(size_t)(m + r) * 512 + n] = f2bf(acc[i][j][r] + bias);
      }
    }
  } else {
    int bb = m0 >> 12, sb = m0 & 4095;
    #pragma unroll
    for (int j = 0; j < 4; j++) {
      int n = n0 + wc * 64 + j * 16 + l15;
      float bias = b4[2 * 512 + n];
      #pragma unroll
      for (int i = 0; i < 4; i++) {
        int s = sb + wr * 64 + i * 16 + l4 * 4;
        ushort4 v;
        v.x = f2bf(acc[i][j][0] + bias);
        v.y = f2bf(acc[i][j][1] + bias);
        v.z = f2bf(acc[i][j][2] + bias);
        v.w = f2bf(acc[i][j][3] + bias);
        *(ushort4*)&VfT[((size_t)bb * CD + n) * SEQ + s] = v;
      }
    }
  }
}

// ---------------- flash attention v3: QBLK=64, KVBLK=32, 8 waves ----------------
// Q fragments in registers (loaded once). K staged in LDS double-buffer via
// global_load_lds (zero VGPR cost). V prefetched into 8 regs at tile start.
// Fixed-max softmax (m=0), 2 raw barriers/tile, 4KB single P buffer.
// QK roles: s = wid&1 (kv strip), g = wid>>1 (q strip) -> no redundancy.
// PV roles: cw = wid&3 (128-c strip), qw = wid>>2 (32-q pair).
__global__ __launch_bounds__(512, 2) void flash_attn(
    const unsigned short* __restrict__ Qf, const unsigned short* __restrict__ Kf,
    const unsigned short* __restrict__ VfT, unsigned short* __restrict__ Ao) {
  __shared__ unsigned short Ks[2][32 * 512];  // 2 x 32KB, chunk-swizzled
  __shared__ unsigned short Ps[64 * 32];      // 4KB, [q][kv] swizzled
  __shared__ float ssum[4][2][16];

  const int t = threadIdx.x;
  const int wid = t >> 6, lane = t & 63;
  const int l15 = lane & 15, l4 = lane >> 4;
  const int s = wid & 1, g = wid >> 1;
  const int cw = wid & 3, qw = wid >> 2;

  const int id = blockIdx.x;
  const int xcd = id & 7;
  const int b = xcd >> 1;
  const int q0 = ((id >> 3) + ((xcd & 1) << 5)) * 64;

  // ---- Q fragments into registers (once): q-strip g, 16 chunks of K=32 ----
  bf16x8 qreg[16];
  {
    const unsigned short* qp = Qf + ((size_t)b * SEQ + q0 + g * 16 + l15) * CD + l4 * 8;
    #pragma unroll
    for (int ck = 0; ck < 16; ck++) qreg[ck] = *(const bf16x8*)(qp + ck * 32);
  }

  const unsigned short* kbT = Kf + (size_t)b * SEQ * CD;
  const unsigned short* vbase = VfT + ((size_t)b * CD + cw * 128 + l15) * SEQ + l4 * 8;

  // ---- prologue: stage K(0) into Ks[0] ----
  #pragma unroll
  for (int i = 0; i < 4; i++) {
    int slot = i * 512 + t;
    int row = slot >> 6, kc = slot & 63;
    int kcs = kc ^ (row & 7);
    gload_lds16(kbT + (size_t)row * CD + kcs * 8, &Ks[0][(size_t)(i * 512 + wid * 64) * 8]);
  }
  VM0;
  __builtin_amdgcn_s_barrier();

  f32x4 acc[8][2];
  #pragma unroll
  for (int i = 0; i < 8; i++) {
    acc[i][0] = (f32x4){0.f, 0.f, 0.f, 0.f};
    acc[i][1] = (f32x4){0.f, 0.f, 0.f, 0.f};
  }
  f32x4 l_acc = (f32x4){0.f, 0.f, 0.f, 0.f};

  int d = 0;
  for (int kv0 = 0; kv0 < SEQ; kv0 += 32, d ^= 1) {
    // ---- 1. stage K(t+1) into Ks[d^1] (stays in flight past mid-barrier) ----
    {
      int kvn = (kv0 + 32 < SEQ) ? kv0 + 32 : kv0;
      const unsigned short* kn = kbT + (size_t)kvn * CD;
      #pragma unroll
      for (int i = 0; i < 4; i++) {
        int slot = i * 512 + t;
        int row = slot >> 6, kc = slot & 63;
        int kcs = kc ^ (row & 7);
        gload_lds16(kn + (size_t)row * CD + kcs * 8, &Ks[d ^ 1][(size_t)(i * 512 + wid * 64) * 8]);
      }
    }
    // ---- 2. V(t) register prefetch (lands during QK) ----
    bf16x8 vr[8];
    #pragma unroll
    for (int i = 0; i < 8; i++) vr[i] = *(const bf16x8*)(vbase + (size_t)i * 16 * SEQ + kv0);

    // ---- 3. QK^T: S[kv strip s][q strip g] from LDS K + reg Q ----
    f32x4 sf = (f32x4){0.f, 0.f, 0.f, 0.f};
    {
      const char* Kb = (const char*)&Ks[d][0];
      const char* krow = Kb + (s * 16 + l15) * 1024;
      const int kswz = (l15 & 7) << 4;
      __builtin_amdgcn_s_setprio(1);
      #pragma unroll
      for (int ck = 0; ck < 16; ck++) {
        bf16x8 kf = *(const bf16x8*)(krow + ((ck * 64 + l4 * 16) ^ kswz));
        sf = MFMA16(kf, qreg[ck], sf);
      }
      __builtin_amdgcn_s_setprio(0);
    }

    // ---- 4. P = exp2(S), accumulate l, write P bf16 to LDS ----
    {
      float p0 = __builtin_amdgcn_exp2f(sf[0]);
      float p1 = __builtin_amdgcn_exp2f(sf[1]);
      float p2 = __builtin_amdgcn_exp2f(sf[2]);
      float p3 = __builtin_amdgcn_exp2f(sf[3]);
      l_acc[0] += p0; l_acc[1] += p1; l_acc[2] += p2; l_acc[3] += p3;
      ushort4 pk;
      pk.x = f2bf(p0); pk.y = f2bf(p1); pk.z = f2bf(p2); pk.w = f2bf(p3);
      int q = g * 16 + l15;
      int off = q * 64 + (((s * 16 + l4 * 4) * 2) ^ ((q & 3) << 4));
      *(ushort4*)((char*)Ps + off) = pk;
    }

    LGKM0;                             // P visible; K(t+1) vmcnt NOT drained
    __builtin_amdgcn_s_barrier();

    // ---- 5. PV: O^T[c strip][q] += V x P^T ----
    __builtin_amdgcn_s_setprio(1);
    #pragma unroll
    for (int jf = 0; jf < 2; jf++) {
      int qv = qw * 32 + jf * 16 + l15;
      bf16x8 pb = *(const bf16x8*)((const char*)Ps + qv * 64 + ((l4 * 16) ^ ((qv & 3) << 4)));
      #pragma unroll
      for (int i = 0; i < 8; i++)
        acc[i][jf] = MFMA16(vr[i], pb, acc[i][jf]);
    }
    __builtin_amdgcn_s_setprio(0);

    VM0;                               // K(t+1) staged before buffer swap
    __builtin_amdgcn_s_barrier();
  }

  // ---- epilogue: reduce l (lanes -> s-waves), normalize, store ----
  float strip = (l_acc[0] + l_acc[1]) + (l_acc[2] + l_acc[3]);
  strip += __shfl_xor(strip, 16, 64);
  strip += __shfl_xor(strip, 32, 64);
  __syncthreads();
  if (lane < 16) ssum[g][s][l15] = strip;
  __syncthreads();

  #pragma unroll
  for (int jf = 0; jf < 2; jf++) {
    int gq = qw * 2 + jf;
    float inv = 1.0f / (ssum[gq][0][l15] + ssum[gq][1][l15]);
    #pragma unroll
    for (int i = 0; i < 8; i++) {
      int c0 = cw * 128 + i * 16 + l4 * 4;
      ushort4 o4;
      o4.x = f2bf(acc[i][jf][0] * inv);
      o4.y = f2bf(acc[i][jf][1] * inv);
      o4.z = f2bf(acc[i][jf][2] * inv);
      o4.w = f2bf(acc[i][jf][3] * inv);
      *(ushort4*)&Ao[((size_t)b * SEQ + q0 + qw * 32 + jf * 16 + l15) * CD + c0] = o4;
    }
  }
}

// ---------------- output projection: out[b][o][s] fp32 ----------------
__global__ __launch_bounds__(256) void gemm_out(
    const unsigned short* __restrict__ W4, const float* __restrict__ b4,
    const unsigned short* __restrict__ Ao, float* __restrict__ out) {
  __shared__ unsigned short As[128 * 64], Bs[128 * 64];
  const int b = blockIdx.z;
  const int n0 = blockIdx.x * 128, m0 = blockIdx.y * 128;
  f32x4 acc[4][4];
  #pragma unroll
  for (int i = 0; i < 4; i++)
    #pragma unroll
    for (int j = 0; j < 4; j++) acc[i][j] = (f32x4){0.f, 0.f, 0.f, 0.f};
  gemm_core(W4 + ((size_t)3 * 512 + m0) * 512, Ao + ((size_t)b * SEQ + n0) * 512, As, Bs, acc);

  const int t = threadIdx.x;
  const int wid = t >> 6, lane = t & 63;
  const int l15 = lane & 15, l4 = lane >> 4;
  const int wr = wid >> 1, wc = wid & 1;
  #pragma unroll
  for (int i = 0; i < 4; i++) {
    int m = m0 + wr * 64 + i * 16 + l4 * 4;
    #pragma unroll
    for (int j = 0; j < 4; j++) {
      int n = n0 + wc * 64 + j * 16 + l15;
      #pragma unroll
      for (int r = 0; r < 4; r++)
        out[((size_t)b * CD + m + r) * SEQ + n] = acc[i][j][r] + b4[3 * 512 + m + r];
    }
  }
}

extern "C" void kernel_launch(void* const* d_in, const int* in_sizes, int n_in,
                              void* d_out, int out_size, void* d_ws, size_t ws_size,
                              hipStream_t stream) {
  (void)in_sizes; (void)n_in; (void)out_size; (void)ws_size;
  const float* q  = (const float*)d_in[0];
  const float* Wq = (const float*)d_in[1];
  const float* bq = (const float*)d_in[2];
  const float* Wk = (const float*)d_in[3];
  const float* bk = (const float*)d_in[4];
  const float* Wv = (const float*)d_in[5];
  const float* bv = (const float*)d_in[6];
  const float* Wo = (const float*)d_in[7];
  const float* bo = (const float*)d_in[8];
  float* out = (float*)d_out;

  char* ws = (char*)d_ws;
  unsigned short* qT  = (unsigned short*)(ws);                     // 16MB (reused as Ao)
  unsigned short* Qf  = (unsigned short*)(ws + ((size_t)16 << 20));
  unsigned short* Kf  = (unsigned short*)(ws + ((size_t)32 << 20));
  unsigned short* VfT = (unsigned short*)(ws + ((size_t)48 << 20));
  unsigned short* W4  = (unsigned short*)(ws + ((size_t)64 << 20)); // 2MB
  float* b4           = (float*)(ws + ((size_t)66 << 20));          // 8KB
  unsigned short* Ao = qT;

  convert_w<<<4096, 256, 0, stream>>>(Wq, Wk, Wv, Wo, bq, bk, bv, bo, W4, b4);
  transpose_q<<<dim3(128, 16, 4), 256, 0, stream>>>(q, qT);
  gemm_proj<<<dim3(4, 128, 3), 256, 0, stream>>>(qT, W4, b4, Qf, Kf, VfT);
  flash_attn<<<256, 512, 0, stream>>>(Qf, Kf, VfT, Ao);
  gemm_out<<<dim3(32, 4, 4), 256, 0, stream>>>(W4, b4, Ao, out);
}

// Round 6
// 390.407 us; speedup vs baseline: 2.5620x; 1.1867x over previous
//
#include <hip/hip_runtime.h>

typedef short bf16x8 __attribute__((ext_vector_type(8)));
typedef float f32x4 __attribute__((ext_vector_type(4)));

#define MFMA16(a, b, c) __builtin_amdgcn_mfma_f32_16x16x32_bf16((a), (b), (c), 0, 0, 0)

#define SEQ 4096
#define CD 512

#define LGKM0 asm volatile("s_waitcnt lgkmcnt(0)" ::: "memory")
#define VM0   asm volatile("s_waitcnt vmcnt(0)" ::: "memory")
#define VMC12 asm volatile("s_waitcnt vmcnt(12)" ::: "memory")

__device__ __forceinline__ unsigned short f2bf(float f) {
  unsigned u = __builtin_bit_cast(unsigned, f);
  u = u + 0x7FFFu + ((u >> 16) & 1u);
  return (unsigned short)(u >> 16);
}

__device__ __forceinline__ void gload_lds16(const void* g, void* l) {
  __builtin_amdgcn_global_load_lds(
      (const __attribute__((address_space(1))) void*)g,
      (__attribute__((address_space(3))) void*)l, 16, 0, 0);
}

// ---------------- weight convert (fp32 -> bf16, fold softmax scale into Wq/bq) ----------------
__global__ __launch_bounds__(256) void convert_w(
    const float* __restrict__ Wq, const float* __restrict__ Wk,
    const float* __restrict__ Wv, const float* __restrict__ Wo,
    const float* __restrict__ bq, const float* __restrict__ bk,
    const float* __restrict__ bv, const float* __restrict__ bo,
    unsigned short* __restrict__ W4, float* __restrict__ b4) {
  int i = blockIdx.x * 256 + threadIdx.x;            // 4*512*512 total
  int p = i >> 18, idx = i & 262143;
  const float sc = 1.4426950408889634f * 0.04419417382415922f;  // log2(e) * 512^-0.5
  const float* W = (p == 0) ? Wq : (p == 1) ? Wk : (p == 2) ? Wv : Wo;
  float v = W[idx] * ((p == 0) ? sc : 1.0f);
  W4[i] = f2bf(v);
  if (idx < 512) {
    const float* bb = (p == 0) ? bq : (p == 1) ? bk : (p == 2) ? bv : bo;
    b4[(p << 9) + idx] = bb[idx] * ((p == 0) ? sc : 1.0f);
  }
}

// ---------------- transpose q: fp32 [b][c][s] -> bf16 qT [b][s][c] ----------------
__global__ __launch_bounds__(256) void transpose_q(
    const float* __restrict__ q, unsigned short* __restrict__ qT) {
  __shared__ float tile[32][33];
  const int b = blockIdx.z, c0 = blockIdx.y * 32, s0 = blockIdx.x * 32;
  const int tx = threadIdx.x & 31, ty = threadIdx.x >> 5;
  #pragma unroll
  for (int i = 0; i < 4; i++) {
    int c = ty + i * 8;
    tile[c][tx] = q[((size_t)b * CD + c0 + c) * SEQ + s0 + tx];
  }
  __syncthreads();
  #pragma unroll
  for (int i = 0; i < 4; i++) {
    int s = ty + i * 8;
    qT[((size_t)b * SEQ + s0 + s) * CD + c0 + tx] = f2bf(tile[tx][s]);
  }
}

// ---------------- shared BT-GEMM core: 128x128 tile, BK=64, 4 waves ----------------
__device__ __forceinline__ void gemm_core(
    const unsigned short* __restrict__ Ap, const unsigned short* __restrict__ Bp,
    unsigned short* As, unsigned short* Bs, f32x4 acc[4][4]) {
  const int t = threadIdx.x;
  const int wid = t >> 6, lane = t & 63;
  const int l15 = lane & 15, l4 = lane >> 4;
  const int wr = wid >> 1, wc = wid & 1;
  for (int k0 = 0; k0 < 512; k0 += 64) {
    #pragma unroll
    for (int j = 0; j < 4; j++) {
      int slot = j * 256 + t;
      int row = slot >> 3, kc = slot & 7;
      int kcs = kc ^ (row & 7);
      gload_lds16(Ap + (size_t)row * 512 + k0 + kcs * 8, As + (j * 256 + wid * 64) * 8);
      gload_lds16(Bp + (size_t)row * 512 + k0 + kcs * 8, Bs + (j * 256 + wid * 64) * 8);
    }
    __syncthreads();
    #pragma unroll
    for (int ks = 0; ks < 2; ks++) {
      bf16x8 af[4], bf[4];
      #pragma unroll
      for (int i = 0; i < 4; i++) {
        int ra = wr * 64 + i * 16 + l15;
        af[i] = *(const bf16x8*)(As + ra * 64 + (((ks << 2) | l4) ^ (ra & 7)) * 8);
        int rb = wc * 64 + i * 16 + l15;
        bf[i] = *(const bf16x8*)(Bs + rb * 64 + (((ks << 2) | l4) ^ (rb & 7)) * 8);
      }
      #pragma unroll
      for (int i = 0; i < 4; i++)
        #pragma unroll
        for (int j = 0; j < 4; j++)
          acc[i][j] = MFMA16(af[i], bf[j], acc[i][j]);
    }
    __syncthreads();
  }
}

// ---------------- QKV projection: z = 0(Q),1(K),2(V transposed) ----------------
__global__ __launch_bounds__(256) void gemm_proj(
    const unsigned short* __restrict__ qT, const unsigned short* __restrict__ W4,
    const float* __restrict__ b4,
    unsigned short* __restrict__ Qf, unsigned short* __restrict__ Kf,
    unsigned short* __restrict__ VfT) {
  __shared__ unsigned short As[128 * 64], Bs[128 * 64];
  const int p = blockIdx.z;
  const int n0 = blockIdx.x * 128, m0 = blockIdx.y * 128;
  f32x4 acc[4][4];
  #pragma unroll
  for (int i = 0; i < 4; i++)
    #pragma unroll
    for (int j = 0; j < 4; j++) acc[i][j] = (f32x4){0.f, 0.f, 0.f, 0.f};
  gemm_core(qT + (size_t)m0 * 512, W4 + ((size_t)p * 512 + n0) * 512, As, Bs, acc);

  const int t = threadIdx.x;
  const int wid = t >> 6, lane = t & 63;
  const int l15 = lane & 15, l4 = lane >> 4;
  const int wr = wid >> 1, wc = wid & 1;

  if (p < 2) {
    unsigned short* out = (p == 0) ? Qf : Kf;
    #pragma unroll
    for (int j = 0; j < 4; j++) {
      int n = n0 + wc * 64 + j * 16 + l15;
      float bias = b4[p * 512 + n];
      #pragma unroll
      for (int i = 0; i < 4; i++) {
        int m = m0 + wr * 64 + i * 16 + l4 * 4;
        #pragma unroll
        for (int r = 0; r < 4; r++)
          out[(size_t)(m + r) * 512 + n] = f2bf(acc[i][j][r] + bias);
      }
    }
  } else {
    int bb = m0 >> 12, sb = m0 & 4095;
    #pragma unroll
    for (int j = 0; j < 4; j++) {
      int n = n0 + wc * 64 + j * 16 + l15;
      float bias = b4[2 * 512 + n];
      #pragma unroll
      for (int i = 0; i < 4; i++) {
        int s = sb + wr * 64 + i * 16 + l4 * 4;
        ushort4 v;
        v.x = f2bf(acc[i][j][0] + bias);
        v.y = f2bf(acc[i][j][1] + bias);
        v.z = f2bf(acc[i][j][2] + bias);
        v.w = f2bf(acc[i][j][3] + bias);
        *(ushort4*)&VfT[((size_t)bb * CD + n) * SEQ + s] = v;
      }
    }
  }
}

// ---------------- flash attention v4: QBLK=64, KVBLK=32, 8 waves, 1 barrier/tile ----------------
// Software pipeline per section t: [issue V(t)] [QK(t) from K-ring] [PV(t-1) from P(t-1)+vr]
// [exp+Pwrite(t)] [stage K(t+2) into 4-deep LDS ring] [lgkm0; vmcnt(12); barrier].
// vmcnt(12): newest 12 vmem = V(t)(8) + staging(t+2)(4) -> drains staging(t+1) (issued a full
// section ago). Fixed-max softmax (m=0). QK roles: s=wid&1 (kv strip), g=wid>>1 (q strip).
// PV roles: cw=wid&3 (128-c strip), qw=wid>>2 (32-q half). V double-buffered in regs (parity).
#define SECTION(T, VRC, VRP, DOPV)                                              \
  {                                                                             \
    const int t_ = (T);                                                         \
    const unsigned short* vt_ = vbase + t_ * 32;                                \
    _Pragma("unroll")                                                           \
    for (int i = 0; i < 8; i++)                                                 \
      VRC[i] = *(const bf16x8*)(vt_ + (size_t)i * 16 * SEQ);                    \
    f32x4 sf = (f32x4){0.f, 0.f, 0.f, 0.f};                                     \
    __builtin_amdgcn_s_setprio(1);                                              \
    {                                                                           \
      const char* krow = (const char*)(Ks + (size_t)(t_ & 3) * 16384) +         \
                         (s * 16 + l15) * 1024;                                 \
      const int kswz = (l15 & 7) << 4;                                          \
      _Pragma("unroll")                                                         \
      for (int ck = 0; ck < 16; ck++) {                                         \
        bf16x8 kf = *(const bf16x8*)(krow + ((ck * 64 + l4 * 16) ^ kswz));      \
        sf = MFMA16(kf, qreg[ck], sf);                                          \
      }                                                                         \
    }                                                                           \
    if (DOPV) {                                                                 \
      _Pragma("unroll")                                                         \
      for (int jf = 0; jf < 2; jf++) {                                          \
        int qv = qw * 32 + jf * 16 + l15;                                       \
        bf16x8 pb = *(const bf16x8*)((const char*)Ps + ((t_ + 1) & 1) * 4096 +  \
                                     qv * 64 +                                  \
                                     ((l4 * 16) ^ (((qv >> 1) & 3) << 4)));     \
        _Pragma("unroll")                                                       \
        for (int i = 0; i < 8; i++)                                             \
          acc[i][jf] = MFMA16(VRP[i], pb, acc[i][jf]);                          \
      }                                                                         \
    }                                                                           \
    __builtin_amdgcn_s_setprio(0);                                              \
    {                                                                           \
      float p0 = __builtin_amdgcn_exp2f(sf[0]);                                 \
      float p1 = __builtin_amdgcn_exp2f(sf[1]);                                 \
      float p2 = __builtin_amdgcn_exp2f(sf[2]);                                 \
      float p3 = __builtin_amdgcn_exp2f(sf[3]);                                 \
      l_acc[0] += p0; l_acc[1] += p1; l_acc[2] += p2; l_acc[3] += p3;           \
      ushort4 pk;                                                               \
      pk.x = f2bf(p0); pk.y = f2bf(p1); pk.z = f2bf(p2); pk.w = f2bf(p3);       \
      int q_ = g * 16 + l15;                                                    \
      int off = (t_ & 1) * 4096 + q_ * 64 +                                     \
                ((s * 32 + l4 * 8) ^ (((q_ >> 1) & 3) << 4));                   \
      *(ushort4*)((char*)Ps + off) = pk;                                        \
    }                                                                           \
    {                                                                           \
      int tt = (t_ + 2 < 128) ? t_ + 2 : 127;                                   \
      const unsigned short* kn = kbT + (size_t)tt * 32 * CD;                    \
      unsigned short* kdst = Ks + (size_t)((t_ + 2) & 3) * 16384;               \
      _Pragma("unroll")                                                         \
      for (int i = 0; i < 4; i++) {                                             \
        int slot = i * 512 + tid;                                               \
        int row = slot >> 6, kc = slot & 63;                                    \
        int kcs = kc ^ (row & 7);                                               \
        gload_lds16(kn + (size_t)row * CD + kcs * 8,                            \
                    kdst + (size_t)(i * 512 + wid * 64) * 8);                   \
      }                                                                         \
    }                                                                           \
    LGKM0;                                                                      \
    VMC12;                                                                      \
    __builtin_amdgcn_s_barrier();                                               \
  }

__global__ __launch_bounds__(512, 2) void flash_attn(
    const unsigned short* __restrict__ Qf, const unsigned short* __restrict__ Kf,
    const unsigned short* __restrict__ VfT, unsigned short* __restrict__ Ao) {
  __shared__ unsigned short Ks[4 * 32 * 512];  // 128KB: 4-deep K ring, chunk-swizzled
  __shared__ unsigned short Ps[2 * 64 * 32];   // 8KB: P double buffer, (q>>1)&3 swizzle
  __shared__ float ssum[4][2][16];

  const int tid = threadIdx.x;
  const int wid = tid >> 6, lane = tid & 63;
  const int l15 = lane & 15, l4 = lane >> 4;
  const int s = wid & 1, g = wid >> 1;
  const int cw = wid & 3, qw = wid >> 2;

  const int id = blockIdx.x;
  const int xcd = id & 7;
  const int b = xcd >> 1;
  const int q0 = ((id >> 3) + ((xcd & 1) << 5)) * 64;

  const unsigned short* kbT = Kf + (size_t)b * SEQ * CD;
  const unsigned short* vbase = VfT + ((size_t)b * CD + cw * 128 + l15) * SEQ + l4 * 8;

  // ---- prologue: stage K(0), K(1) into ring slots 0,1 ----
  #pragma unroll
  for (int tt = 0; tt < 2; tt++) {
    const unsigned short* kn = kbT + (size_t)tt * 32 * CD;
    unsigned short* kdst = Ks + (size_t)tt * 16384;
    #pragma unroll
    for (int i = 0; i < 4; i++) {
      int slot = i * 512 + tid;
      int row = slot >> 6, kc = slot & 63;
      int kcs = kc ^ (row & 7);
      gload_lds16(kn + (size_t)row * CD + kcs * 8, kdst + (size_t)(i * 512 + wid * 64) * 8);
    }
  }

  // ---- Q fragments into registers (once): q-strip g ----
  bf16x8 qreg[16];
  {
    const unsigned short* qp = Qf + ((size_t)b * SEQ + q0 + g * 16 + l15) * CD + l4 * 8;
    #pragma unroll
    for (int ck = 0; ck < 16; ck++) qreg[ck] = *(const bf16x8*)(qp + ck * 32);
  }

  f32x4 acc[8][2];
  #pragma unroll
  for (int i = 0; i < 8; i++) {
    acc[i][0] = (f32x4){0.f, 0.f, 0.f, 0.f};
    acc[i][1] = (f32x4){0.f, 0.f, 0.f, 0.f};
  }
  f32x4 l_acc = (f32x4){0.f, 0.f, 0.f, 0.f};

  bf16x8 vrA[8], vrB[8];

  VM0;   // K(0),K(1) staged + qreg loaded
  __builtin_amdgcn_s_barrier();

  // ---- pipelined main loop: 128 sections, one barrier each ----
  SECTION(0, vrA, vrB, 0);
  for (int t = 1; t < 127; t += 2) {
    SECTION(t, vrB, vrA, 1);
    SECTION(t + 1, vrA, vrB, 1);
  }
  SECTION(127, vrB, vrA, 1);

  // ---- epilogue PV(127): P in buffer 1, V in vrB ----
  #pragma unroll
  for (int jf = 0; jf < 2; jf++) {
    int qv = qw * 32 + jf * 16 + l15;
    bf16x8 pb = *(const bf16x8*)((const char*)Ps + 4096 + qv * 64 +
                                 ((l4 * 16) ^ (((qv >> 1) & 3) << 4)));
    #pragma unroll
    for (int i = 0; i < 8; i++)
      acc[i][jf] = MFMA16(vrB[i], pb, acc[i][jf]);
  }

  // ---- l reduce (lanes -> s waves), normalize, store ----
  float strip = (l_acc[0] + l_acc[1]) + (l_acc[2] + l_acc[3]);
  strip += __shfl_xor(strip, 16, 64);
  strip += __shfl_xor(strip, 32, 64);
  __syncthreads();
  if (lane < 16) ssum[g][s][l15] = strip;
  __syncthreads();

  #pragma unroll
  for (int jf = 0; jf < 2; jf++) {
    int gq = qw * 2 + jf;
    float inv = 1.0f / (ssum[gq][0][l15] + ssum[gq][1][l15]);
    #pragma unroll
    for (int i = 0; i < 8; i++) {
      int c0 = cw * 128 + i * 16 + l4 * 4;
      ushort4 o4;
      o4.x = f2bf(acc[i][jf][0] * inv);
      o4.y = f2bf(acc[i][jf][1] * inv);
      o4.z = f2bf(acc[i][jf][2] * inv);
      o4.w = f2bf(acc[i][jf][3] * inv);
      *(ushort4*)&Ao[((size_t)b * SEQ + q0 + qw * 32 + jf * 16 + l15) * CD + c0] = o4;
    }
  }
}

// ---------------- output projection: out[b][o][s] fp32 ----------------
__global__ __launch_bounds__(256) void gemm_out(
    const unsigned short* __restrict__ W4, const float* __restrict__ b4,
    const unsigned short* __restrict__ Ao, float* __restrict__ out) {
  __shared__ unsigned short As[128 * 64], Bs[128 * 64];
  const int b = blockIdx.z;
  const int n0 = blockIdx.x * 128, m0 = blockIdx.y * 128;
  f32x4 acc[4][4];
  #pragma unroll
  for (int i = 0; i < 4; i++)
    #pragma unroll
    for (int j = 0; j < 4; j++) acc[i][j] = (f32x4){0.f, 0.f, 0.f, 0.f};
  gemm_core(W4 + ((size_t)3 * 512 + m0) * 512, Ao + ((size_t)b * SEQ + n0) * 512, As, Bs, acc);

  const int t = threadIdx.x;
  const int wid = t >> 6, lane = t & 63;
  const int l15 = lane & 15, l4 = lane >> 4;
  const int wr = wid >> 1, wc = wid & 1;
  #pragma unroll
  for (int i = 0; i < 4; i++) {
    int m = m0 + wr * 64 + i * 16 + l4 * 4;
    #pragma unroll
    for (int j = 0; j < 4; j++) {
      int n = n0 + wc * 64 + j * 16 + l15;
      #pragma unroll
      for (int r = 0; r < 4; r++)
        out[((size_t)b * CD + m + r) * SEQ + n] = acc[i][j][r] + b4[3 * 512 + m + r];
    }
  }
}

extern "C" void kernel_launch(void* const* d_in, const int* in_sizes, int n_in,
                              void* d_out, int out_size, void* d_ws, size_t ws_size,
                              hipStream_t stream) {
  (void)in_sizes; (void)n_in; (void)out_size; (void)ws_size;
  const float* q  = (const float*)d_in[0];
  const float* Wq = (const float*)d_in[1];
  const float* bq = (const float*)d_in[2];
  const float* Wk = (const float*)d_in[3];
  const float* bk = (const float*)d_in[4];
  const float* Wv = (const float*)d_in[5];
  const float* bv = (const float*)d_in[6];
  const float* Wo = (const float*)d_in[7];
  const float* bo = (const float*)d_in[8];
  float* out = (float*)d_out;

  char* ws = (char*)d_ws;
  unsigned short* qT  = (unsigned short*)(ws);                     // 16MB (reused as Ao)
  unsigned short* Qf  = (unsigned short*)(ws + ((size_t)16 << 20));
  unsigned short* Kf  = (unsigned short*)(ws + ((size_t)32 << 20));
  unsigned short* VfT = (unsigned short*)(ws + ((size_t)48 << 20));
  unsigned short* W4  = (unsigned short*)(ws + ((size_t)64 << 20)); // 2MB
  float* b4           = (float*)(ws + ((size_t)66 << 20));          // 8KB
  unsigned short* Ao = qT;

  convert_w<<<4096, 256, 0, stream>>>(Wq, Wk, Wv, Wo, bq, bk, bv, bo, W4, b4);
  transpose_q<<<dim3(128, 16, 4), 256, 0, stream>>>(q, qT);
  gemm_proj<<<dim3(4, 128, 3), 256, 0, stream>>>(qT, W4, b4, Qf, Kf, VfT);
  flash_attn<<<256, 512, 0, stream>>>(Qf, Kf, VfT, Ao);
  gemm_out<<<dim3(32, 4, 4), 256, 0, stream>>>(W4, b4, Ao, out);
}

// Round 7
// 338.689 us; speedup vs baseline: 2.9532x; 1.1527x over previous
//
#include <hip/hip_runtime.h>

typedef short bf16x8 __attribute__((ext_vector_type(8)));
typedef float f32x4 __attribute__((ext_vector_type(4)));

#define MFMA16(a, b, c) __builtin_amdgcn_mfma_f32_16x16x32_bf16((a), (b), (c), 0, 0, 0)

#define SEQ 4096
#define CD 512

#define LGKM0 asm volatile("s_waitcnt lgkmcnt(0)" ::: "memory")
#define VM0   asm volatile("s_waitcnt vmcnt(0)" ::: "memory")
#define VMC12 asm volatile("s_waitcnt vmcnt(12)" ::: "memory")

__device__ __forceinline__ unsigned short f2bf(float f) {
  unsigned u = __builtin_bit_cast(unsigned, f);
  u = u + 0x7FFFu + ((u >> 16) & 1u);
  return (unsigned short)(u >> 16);
}

__device__ __forceinline__ void gload_lds16(const void* g, void* l) {
  __builtin_amdgcn_global_load_lds(
      (const __attribute__((address_space(1))) void*)g,
      (__attribute__((address_space(3))) void*)l, 16, 0, 0);
}

// ---------------- weight convert (fp32 -> bf16, fold softmax scale into Wq/bq) ----------------
__global__ __launch_bounds__(256) void convert_w(
    const float* __restrict__ Wq, const float* __restrict__ Wk,
    const float* __restrict__ Wv, const float* __restrict__ Wo,
    const float* __restrict__ bq, const float* __restrict__ bk,
    const float* __restrict__ bv, const float* __restrict__ bo,
    unsigned short* __restrict__ W4, float* __restrict__ b4) {
  int i = blockIdx.x * 256 + threadIdx.x;            // 4*512*512 total
  int p = i >> 18, idx = i & 262143;
  const float sc = 1.4426950408889634f * 0.04419417382415922f;  // log2(e) * 512^-0.5
  const float* W = (p == 0) ? Wq : (p == 1) ? Wk : (p == 2) ? Wv : Wo;
  float v = W[idx] * ((p == 0) ? sc : 1.0f);
  W4[i] = f2bf(v);
  if (idx < 512) {
    const float* bb = (p == 0) ? bq : (p == 1) ? bk : (p == 2) ? bv : bo;
    b4[(p << 9) + idx] = bb[idx] * ((p == 0) ? sc : 1.0f);
  }
}

// ---------------- transpose q: fp32 [b][c][s] -> bf16 qT [b][s][c] ----------------
__global__ __launch_bounds__(256) void transpose_q(
    const float* __restrict__ q, unsigned short* __restrict__ qT) {
  __shared__ float tile[32][33];
  const int b = blockIdx.z, c0 = blockIdx.y * 32, s0 = blockIdx.x * 32;
  const int tx = threadIdx.x & 31, ty = threadIdx.x >> 5;
  #pragma unroll
  for (int i = 0; i < 4; i++) {
    int c = ty + i * 8;
    tile[c][tx] = q[((size_t)b * CD + c0 + c) * SEQ + s0 + tx];
  }
  __syncthreads();
  #pragma unroll
  for (int i = 0; i < 4; i++) {
    int s = ty + i * 8;
    qT[((size_t)b * SEQ + s0 + s) * CD + c0 + tx] = f2bf(tile[tx][s]);
  }
}

// ---------------- generalized BT-GEMM core: 128x128 tile, BK=64, 4 waves ----------------
// C[m][n] = sum_k A[m][k] * B[n][k], A rows ld = lda, B rows ld = ldb, K = kmax.
__device__ __forceinline__ void gemm_core2(
    const unsigned short* __restrict__ Ap, size_t lda,
    const unsigned short* __restrict__ Bp, size_t ldb, int kmax,
    unsigned short* As, unsigned short* Bs, f32x4 acc[4][4]) {
  const int t = threadIdx.x;
  const int wid = t >> 6, lane = t & 63;
  const int l15 = lane & 15, l4 = lane >> 4;
  const int wr = wid >> 1, wc = wid & 1;
  for (int k0 = 0; k0 < kmax; k0 += 64) {
    #pragma unroll
    for (int j = 0; j < 4; j++) {
      int slot = j * 256 + t;
      int row = slot >> 3, kc = slot & 7;
      int kcs = kc ^ (row & 7);
      gload_lds16(Ap + (size_t)row * lda + k0 + kcs * 8, As + (j * 256 + wid * 64) * 8);
      gload_lds16(Bp + (size_t)row * ldb + k0 + kcs * 8, Bs + (j * 256 + wid * 64) * 8);
    }
    __syncthreads();
    #pragma unroll
    for (int ks = 0; ks < 2; ks++) {
      bf16x8 af[4], bf[4];
      #pragma unroll
      for (int i = 0; i < 4; i++) {
        int ra = wr * 64 + i * 16 + l15;
        af[i] = *(const bf16x8*)(As + ra * 64 + (((ks << 2) | l4) ^ (ra & 7)) * 8);
        int rb = wc * 64 + i * 16 + l15;
        bf[i] = *(const bf16x8*)(Bs + rb * 64 + (((ks << 2) | l4) ^ (rb & 7)) * 8);
      }
      #pragma unroll
      for (int i = 0; i < 4; i++)
        #pragma unroll
        for (int j = 0; j < 4; j++)
          acc[i][j] = MFMA16(af[i], bf[j], acc[i][j]);
    }
    __syncthreads();
  }
}

__device__ __forceinline__ void gemm_core(
    const unsigned short* __restrict__ Ap, const unsigned short* __restrict__ Bp,
    unsigned short* As, unsigned short* Bs, f32x4 acc[4][4]) {
  gemm_core2(Ap, 512, Bp, 512, 512, As, Bs, acc);
}

// ---------------- QKV projection: z = 0(Q),1(K),2(V transposed) ----------------
__global__ __launch_bounds__(256) void gemm_proj(
    const unsigned short* __restrict__ qT, const unsigned short* __restrict__ W4,
    const float* __restrict__ b4,
    unsigned short* __restrict__ Qf, unsigned short* __restrict__ Kf,
    unsigned short* __restrict__ VfT) {
  __shared__ unsigned short As[128 * 64], Bs[128 * 64];
  const int p = blockIdx.z;
  const int n0 = blockIdx.x * 128, m0 = blockIdx.y * 128;
  f32x4 acc[4][4];
  #pragma unroll
  for (int i = 0; i < 4; i++)
    #pragma unroll
    for (int j = 0; j < 4; j++) acc[i][j] = (f32x4){0.f, 0.f, 0.f, 0.f};
  gemm_core(qT + (size_t)m0 * 512, W4 + ((size_t)p * 512 + n0) * 512, As, Bs, acc);

  const int t = threadIdx.x;
  const int wid = t >> 6, lane = t & 63;
  const int l15 = lane & 15, l4 = lane >> 4;
  const int wr = wid >> 1, wc = wid & 1;

  if (p < 2) {
    unsigned short* out = (p == 0) ? Qf : Kf;
    #pragma unroll
    for (int j = 0; j < 4; j++) {
      int n = n0 + wc * 64 + j * 16 + l15;
      float bias = b4[p * 512 + n];
      #pragma unroll
      for (int i = 0; i < 4; i++) {
        int m = m0 + wr * 64 + i * 16 + l4 * 4;
        #pragma unroll
        for (int r = 0; r < 4; r++)
          out[(size_t)(m + r) * 512 + n] = f2bf(acc[i][j][r] + bias);
      }
    }
  } else {
    int bb = m0 >> 12, sb = m0 & 4095;
    #pragma unroll
    for (int j = 0; j < 4; j++) {
      int n = n0 + wc * 64 + j * 16 + l15;
      float bias = b4[2 * 512 + n];
      #pragma unroll
      for (int i = 0; i < 4; i++) {
        int s = sb + wr * 64 + i * 16 + l4 * 4;
        ushort4 v;
        v.x = f2bf(acc[i][j][0] + bias);
        v.y = f2bf(acc[i][j][1] + bias);
        v.z = f2bf(acc[i][j][2] + bias);
        v.w = f2bf(acc[i][j][3] + bias);
        *(ushort4*)&VfT[((size_t)bb * CD + n) * SEQ + s] = v;
      }
    }
  }
}

// ---------------- QK^T GEMM with fused exp2 + row-partial-sum epilogue ----------------
// P[q][k] = exp2(Q[q]·K[k]) (scale pre-folded, fixed max 0), partials[q][ktile] = row sums.
__global__ __launch_bounds__(256) void gemm_qk(
    const unsigned short* __restrict__ Qf, const unsigned short* __restrict__ Kf,
    unsigned short* __restrict__ P, float* __restrict__ partials, int bbase) {
  __shared__ unsigned short As[128 * 64], Bs[128 * 64];
  __shared__ float ssum[2][2][64];
  const int z = blockIdx.z, b = bbase + z;
  const int n0 = blockIdx.x * 128, m0 = blockIdx.y * 128;
  f32x4 acc[4][4];
  #pragma unroll
  for (int i = 0; i < 4; i++)
    #pragma unroll
    for (int j = 0; j < 4; j++) acc[i][j] = (f32x4){0.f, 0.f, 0.f, 0.f};
  gemm_core2(Qf + ((size_t)b * SEQ + m0) * CD, CD,
             Kf + ((size_t)b * SEQ + n0) * CD, CD, CD, As, Bs, acc);

  const int t = threadIdx.x;
  const int wid = t >> 6, lane = t & 63;
  const int l15 = lane & 15, l4 = lane >> 4;
  const int wr = wid >> 1, wc = wid & 1;
  unsigned short* Pz = P + (size_t)z * SEQ * SEQ;

  float rsum[16];
  #pragma unroll
  for (int v = 0; v < 16; v++) rsum[v] = 0.f;

  #pragma unroll
  for (int i = 0; i < 4; i++) {
    int m = m0 + wr * 64 + i * 16 + l4 * 4;
    #pragma unroll
    for (int j = 0; j < 4; j++) {
      int n = n0 + wc * 64 + j * 16 + l15;
      float p0 = __builtin_amdgcn_exp2f(acc[i][j][0]);
      float p1 = __builtin_amdgcn_exp2f(acc[i][j][1]);
      float p2 = __builtin_amdgcn_exp2f(acc[i][j][2]);
      float p3 = __builtin_amdgcn_exp2f(acc[i][j][3]);
      rsum[i * 4 + 0] += p0; rsum[i * 4 + 1] += p1;
      rsum[i * 4 + 2] += p2; rsum[i * 4 + 3] += p3;
      Pz[(size_t)(m + 0) * SEQ + n] = f2bf(p0);
      Pz[(size_t)(m + 1) * SEQ + n] = f2bf(p1);
      Pz[(size_t)(m + 2) * SEQ + n] = f2bf(p2);
      Pz[(size_t)(m + 3) * SEQ + n] = f2bf(p3);
    }
  }
  // reduce over the 16 lanes sharing the same row (l15 bits)
  #pragma unroll
  for (int v = 0; v < 16; v++) {
    float s = rsum[v];
    s += __shfl_xor(s, 1, 64);
    s += __shfl_xor(s, 2, 64);
    s += __shfl_xor(s, 4, 64);
    s += __shfl_xor(s, 8, 64);
    rsum[v] = s;
  }
  if (l15 == 0) {
    #pragma unroll
    for (int i = 0; i < 4; i++)
      #pragma unroll
      for (int r = 0; r < 4; r++)
        ssum[wr][wc][i * 16 + l4 * 4 + r] = rsum[i * 4 + r];
  }
  __syncthreads();
  if (t < 128) {
    float s = ssum[t >> 6][0][t & 63] + ssum[t >> 6][1][t & 63];
    partials[((size_t)z * SEQ + m0 + t) * 32 + blockIdx.x] = s;
  }
}

// ---------------- l reduce: linv[q] = 1 / sum_32 partials[q][.] ----------------
__global__ __launch_bounds__(256) void reduce_l(
    const float* __restrict__ partials, float* __restrict__ linv) {
  int i = blockIdx.x * 256 + threadIdx.x;
  const float* p = partials + (size_t)i * 32;
  float s = 0.f;
  #pragma unroll
  for (int j = 0; j < 32; j++) s += p[j];
  linv[i] = 1.0f / s;
}

// ---------------- PV GEMM: Ao[q][c] = (sum_s P[q][s] V[s][c]) * linv[q] ----------------
// C[m=c][n=q] = sum_s VfT[c][s] * P[q][s]
__global__ __launch_bounds__(256) void gemm_pv(
    const unsigned short* __restrict__ VfT, const unsigned short* __restrict__ P,
    const float* __restrict__ linv, unsigned short* __restrict__ Ao, int bbase) {
  __shared__ unsigned short As[128 * 64], Bs[128 * 64];
  const int z = blockIdx.z, b = bbase + z;
  const int n0 = blockIdx.x * 128, m0 = blockIdx.y * 128;
  f32x4 acc[4][4];
  #pragma unroll
  for (int i = 0; i < 4; i++)
    #pragma unroll
    for (int j = 0; j < 4; j++) acc[i][j] = (f32x4){0.f, 0.f, 0.f, 0.f};
  gemm_core2(VfT + ((size_t)b * CD + m0) * SEQ, SEQ,
             P + (size_t)z * SEQ * SEQ + (size_t)n0 * SEQ, SEQ, SEQ, As, Bs, acc);

  const int t = threadIdx.x;
  const int wid = t >> 6, lane = t & 63;
  const int l15 = lane & 15, l4 = lane >> 4;
  const int wr = wid >> 1, wc = wid & 1;
  #pragma unroll
  for (int j = 0; j < 4; j++) {
    int n = n0 + wc * 64 + j * 16 + l15;        // q
    float inv = linv[(size_t)z * SEQ + n];
    #pragma unroll
    for (int i = 0; i < 4; i++) {
      int m = m0 + wr * 64 + i * 16 + l4 * 4;   // c
      ushort4 o4;
      o4.x = f2bf(acc[i][j][0] * inv);
      o4.y = f2bf(acc[i][j][1] * inv);
      o4.z = f2bf(acc[i][j][2] * inv);
      o4.w = f2bf(acc[i][j][3] * inv);
      *(ushort4*)&Ao[((size_t)b * SEQ + n) * CD + m] = o4;
    }
  }
}

// ---------------- flash attention v4 (fallback when workspace is small) ----------------
#define SECTION(T, VRC, VRP, DOPV)                                              \
  {                                                                             \
    const int t_ = (T);                                                         \
    const unsigned short* vt_ = vbase + t_ * 32;                                \
    _Pragma("unroll")                                                           \
    for (int i = 0; i < 8; i++)                                                 \
      VRC[i] = *(const bf16x8*)(vt_ + (size_t)i * 16 * SEQ);                    \
    f32x4 sf = (f32x4){0.f, 0.f, 0.f, 0.f};                                     \
    __builtin_amdgcn_s_setprio(1);                                              \
    {                                                                           \
      const char* krow = (const char*)(Ks + (size_t)(t_ & 3) * 16384) +         \
                         (s * 16 + l15) * 1024;                                 \
      const int kswz = (l15 & 7) << 4;                                          \
      _Pragma("unroll")                                                         \
      for (int ck = 0; ck < 16; ck++) {                                         \
        bf16x8 kf = *(const bf16x8*)(krow + ((ck * 64 + l4 * 16) ^ kswz));      \
        sf = MFMA16(kf, qreg[ck], sf);                                          \
      }                                                                         \
    }                                                                           \
    if (DOPV) {                                                                 \
      _Pragma("unroll")                                                         \
      for (int jf = 0; jf < 2; jf++) {                                          \
        int qv = qw * 32 + jf * 16 + l15;                                       \
        bf16x8 pb = *(const bf16x8*)((const char*)Ps + ((t_ + 1) & 1) * 4096 +  \
                                     qv * 64 +                                  \
                                     ((l4 * 16) ^ (((qv >> 1) & 3) << 4)));     \
        _Pragma("unroll")                                                       \
        for (int i = 0; i < 8; i++)                                             \
          acc[i][jf] = MFMA16(VRP[i], pb, acc[i][jf]);                          \
      }                                                                         \
    }                                                                           \
    __builtin_amdgcn_s_setprio(0);                                              \
    {                                                                           \
      float p0 = __builtin_amdgcn_exp2f(sf[0]);                                 \
      float p1 = __builtin_amdgcn_exp2f(sf[1]);                                 \
      float p2 = __builtin_amdgcn_exp2f(sf[2]);                                 \
      float p3 = __builtin_amdgcn_exp2f(sf[3]);                                 \
      l_acc[0] += p0; l_acc[1] += p1; l_acc[2] += p2; l_acc[3] += p3;           \
      ushort4 pk;                                                               \
      pk.x = f2bf(p0); pk.y = f2bf(p1); pk.z = f2bf(p2); pk.w = f2bf(p3);       \
      int q_ = g * 16 + l15;                                                    \
      int off = (t_ & 1) * 4096 + q_ * 64 +                                     \
                ((s * 32 + l4 * 8) ^ (((q_ >> 1) & 3) << 4));                   \
      *(ushort4*)((char*)Ps + off) = pk;                                        \
    }                                                                           \
    {                                                                           \
      int tt = (t_ + 2 < 128) ? t_ + 2 : 127;                                   \
      const unsigned short* kn = kbT + (size_t)tt * 32 * CD;                    \
      unsigned short* kdst = Ks + (size_t)((t_ + 2) & 3) * 16384;               \
      _Pragma("unroll")                                                         \
      for (int i = 0; i < 4; i++) {                                             \
        int slot = i * 512 + tid;                                               \
        int row = slot >> 6, kc = slot & 63;                                    \
        int kcs = kc ^ (row & 7);                                               \
        gload_lds16(kn + (size_t)row * CD + kcs * 8,                            \
                    kdst + (size_t)(i * 512 + wid * 64) * 8);                   \
      }                                                                         \
    }                                                                           \
    LGKM0;                                                                      \
    VMC12;                                                                      \
    __builtin_amdgcn_s_barrier();                                               \
  }

__global__ __launch_bounds__(512, 2) void flash_attn(
    const unsigned short* __restrict__ Qf, const unsigned short* __restrict__ Kf,
    const unsigned short* __restrict__ VfT, unsigned short* __restrict__ Ao) {
  __shared__ unsigned short Ks[4 * 32 * 512];
  __shared__ unsigned short Ps[2 * 64 * 32];
  __shared__ float ssum[4][2][16];

  const int tid = threadIdx.x;
  const int wid = tid >> 6, lane = tid & 63;
  const int l15 = lane & 15, l4 = lane >> 4;
  const int s = wid & 1, g = wid >> 1;
  const int cw = wid & 3, qw = wid >> 2;

  const int id = blockIdx.x;
  const int xcd = id & 7;
  const int b = xcd >> 1;
  const int q0 = ((id >> 3) + ((xcd & 1) << 5)) * 64;

  const unsigned short* kbT = Kf + (size_t)b * SEQ * CD;
  const unsigned short* vbase = VfT + ((size_t)b * CD + cw * 128 + l15) * SEQ + l4 * 8;

  #pragma unroll
  for (int tt = 0; tt < 2; tt++) {
    const unsigned short* kn = kbT + (size_t)tt * 32 * CD;
    unsigned short* kdst = Ks + (size_t)tt * 16384;
    #pragma unroll
    for (int i = 0; i < 4; i++) {
      int slot = i * 512 + tid;
      int row = slot >> 6, kc = slot & 63;
      int kcs = kc ^ (row & 7);
      gload_lds16(kn + (size_t)row * CD + kcs * 8, kdst + (size_t)(i * 512 + wid * 64) * 8);
    }
  }

  bf16x8 qreg[16];
  {
    const unsigned short* qp = Qf + ((size_t)b * SEQ + q0 + g * 16 + l15) * CD + l4 * 8;
    #pragma unroll
    for (int ck = 0; ck < 16; ck++) qreg[ck] = *(const bf16x8*)(qp + ck * 32);
  }

  f32x4 acc[8][2];
  #pragma unroll
  for (int i = 0; i < 8; i++) {
    acc[i][0] = (f32x4){0.f, 0.f, 0.f, 0.f};
    acc[i][1] = (f32x4){0.f, 0.f, 0.f, 0.f};
  }
  f32x4 l_acc = (f32x4){0.f, 0.f, 0.f, 0.f};

  bf16x8 vrA[8], vrB[8];

  VM0;
  __builtin_amdgcn_s_barrier();

  SECTION(0, vrA, vrB, 0);
  for (int t = 1; t < 127; t += 2) {
    SECTION(t, vrB, vrA, 1);
    SECTION(t + 1, vrA, vrB, 1);
  }
  SECTION(127, vrB, vrA, 1);

  #pragma unroll
  for (int jf = 0; jf < 2; jf++) {
    int qv = qw * 32 + jf * 16 + l15;
    bf16x8 pb = *(const bf16x8*)((const char*)Ps + 4096 + qv * 64 +
                                 ((l4 * 16) ^ (((qv >> 1) & 3) << 4)));
    #pragma unroll
    for (int i = 0; i < 8; i++)
      acc[i][jf] = MFMA16(vrB[i], pb, acc[i][jf]);
  }

  float strip = (l_acc[0] + l_acc[1]) + (l_acc[2] + l_acc[3]);
  strip += __shfl_xor(strip, 16, 64);
  strip += __shfl_xor(strip, 32, 64);
  __syncthreads();
  if (lane < 16) ssum[g][s][l15] = strip;
  __syncthreads();

  #pragma unroll
  for (int jf = 0; jf < 2; jf++) {
    int gq = qw * 2 + jf;
    float inv = 1.0f / (ssum[gq][0][l15] + ssum[gq][1][l15]);
    #pragma unroll
    for (int i = 0; i < 8; i++) {
      int c0 = cw * 128 + i * 16 + l4 * 4;
      ushort4 o4;
      o4.x = f2bf(acc[i][jf][0] * inv);
      o4.y = f2bf(acc[i][jf][1] * inv);
      o4.z = f2bf(acc[i][jf][2] * inv);
      o4.w = f2bf(acc[i][jf][3] * inv);
      *(ushort4*)&Ao[((size_t)b * SEQ + q0 + qw * 32 + jf * 16 + l15) * CD + c0] = o4;
    }
  }
}

// ---------------- output projection: out[b][o][s] fp32 ----------------
__global__ __launch_bounds__(256) void gemm_out(
    const unsigned short* __restrict__ W4, const float* __restrict__ b4,
    const unsigned short* __restrict__ Ao, float* __restrict__ out) {
  __shared__ unsigned short As[128 * 64], Bs[128 * 64];
  const int b = blockIdx.z;
  const int n0 = blockIdx.x * 128, m0 = blockIdx.y * 128;
  f32x4 acc[4][4];
  #pragma unroll
  for (int i = 0; i < 4; i++)
    #pragma unroll
    for (int j = 0; j < 4; j++) acc[i][j] = (f32x4){0.f, 0.f, 0.f, 0.f};
  gemm_core(W4 + ((size_t)3 * 512 + m0) * 512, Ao + ((size_t)b * SEQ + n0) * 512, As, Bs, acc);

  const int t = threadIdx.x;
  const int wid = t >> 6, lane = t & 63;
  const int l15 = lane & 15, l4 = lane >> 4;
  const int wr = wid >> 1, wc = wid & 1;
  #pragma unroll
  for (int i = 0; i < 4; i++) {
    int m = m0 + wr * 64 + i * 16 + l4 * 4;
    #pragma unroll
    for (int j = 0; j < 4; j++) {
      int n = n0 + wc * 64 + j * 16 + l15;
      #pragma unroll
      for (int r = 0; r < 4; r++)
        out[((size_t)b * CD + m + r) * SEQ + n] = acc[i][j][r] + b4[3 * 512 + m + r];
    }
  }
}

extern "C" void kernel_launch(void* const* d_in, const int* in_sizes, int n_in,
                              void* d_out, int out_size, void* d_ws, size_t ws_size,
                              hipStream_t stream) {
  (void)in_sizes; (void)n_in; (void)out_size;
  const float* q  = (const float*)d_in[0];
  const float* Wq = (const float*)d_in[1];
  const float* bq = (const float*)d_in[2];
  const float* Wk = (const float*)d_in[3];
  const float* bk = (const float*)d_in[4];
  const float* Wv = (const float*)d_in[5];
  const float* bv = (const float*)d_in[6];
  const float* Wo = (const float*)d_in[7];
  const float* bo = (const float*)d_in[8];
  float* out = (float*)d_out;

  char* ws = (char*)d_ws;
  const size_t MB = (size_t)1 << 20;
  unsigned short* qT  = (unsigned short*)(ws);            // 16MB (reused as Ao)
  unsigned short* Qf  = (unsigned short*)(ws + 16 * MB);
  unsigned short* Kf  = (unsigned short*)(ws + 32 * MB);
  unsigned short* VfT = (unsigned short*)(ws + 48 * MB);
  unsigned short* W4  = (unsigned short*)(ws + 64 * MB);  // 2MB
  float* b4           = (float*)(ws + 66 * MB);           // 8KB
  unsigned short* Pbuf = (unsigned short*)(ws + 67 * MB); // 32 or 64 MB
  unsigned short* Ao = qT;

  convert_w<<<4096, 256, 0, stream>>>(Wq, Wk, Wv, Wo, bq, bk, bv, bo, W4, b4);
  transpose_q<<<dim3(128, 16, 4), 256, 0, stream>>>(q, qT);
  gemm_proj<<<dim3(4, 128, 3), 256, 0, stream>>>(qT, W4, b4, Qf, Kf, VfT);

  if (ws_size >= 134 * MB) {
    // pair path: P holds 2 batches (64MB), partials at 131MB, linv at 132.5MB
    float* partials = (float*)(ws + 131 * MB);            // 2*4096*32*4 = 1MB
    float* linv     = (float*)(ws + (132 * MB + 512 * 1024));
    for (int pr = 0; pr < 2; ++pr) {
      gemm_qk<<<dim3(32, 32, 2), 256, 0, stream>>>(Qf, Kf, Pbuf, partials, pr * 2);
      reduce_l<<<32, 256, 0, stream>>>(partials, linv);
      gemm_pv<<<dim3(32, 4, 2), 256, 0, stream>>>(VfT, Pbuf, linv, Ao, pr * 2);
    }
  } else if (ws_size >= 101 * MB) {
    // per-batch path: P holds 1 batch (32MB), partials at 99MB, linv at 99.75MB
    float* partials = (float*)(ws + 99 * MB);             // 4096*32*4 = 512KB
    float* linv     = (float*)(ws + (99 * MB + 768 * 1024));
    for (int bb = 0; bb < 4; ++bb) {
      gemm_qk<<<dim3(32, 32, 1), 256, 0, stream>>>(Qf, Kf, Pbuf, partials, bb);
      reduce_l<<<16, 256, 0, stream>>>(partials, linv);
      gemm_pv<<<dim3(32, 4, 1), 256, 0, stream>>>(VfT, Pbuf, linv, Ao, bb);
    }
  } else {
    flash_attn<<<256, 512, 0, stream>>>(Qf, Kf, VfT, Ao);
  }

  gemm_out<<<dim3(32, 4, 4), 256, 0, stream>>>(W4, b4, Ao, out);
}

// Round 8
// 299.368 us; speedup vs baseline: 3.3411x; 1.1313x over previous
//
#include <hip/hip_runtime.h>

typedef short bf16x8 __attribute__((ext_vector_type(8)));
typedef float f32x4 __attribute__((ext_vector_type(4)));

#define MFMA16(a, b, c) __builtin_amdgcn_mfma_f32_16x16x32_bf16((a), (b), (c), 0, 0, 0)

#define SEQ 4096
#define CD 512

#define LGKM0 asm volatile("s_waitcnt lgkmcnt(0)" ::: "memory")
#define VM0   asm volatile("s_waitcnt vmcnt(0)" ::: "memory")
#define VMC12 asm volatile("s_waitcnt vmcnt(12)" ::: "memory")

__device__ __forceinline__ unsigned short f2bf(float f) {
  unsigned u = __builtin_bit_cast(unsigned, f);
  u = u + 0x7FFFu + ((u >> 16) & 1u);
  return (unsigned short)(u >> 16);
}

__device__ __forceinline__ void gload_lds16(const void* g, void* l) {
  __builtin_amdgcn_global_load_lds(
      (const __attribute__((address_space(1))) void*)g,
      (__attribute__((address_space(3))) void*)l, 16, 0, 0);
}

// ---------------- weight convert (fp32 -> bf16, fold softmax scale into Wq/bq) ----------------
__global__ __launch_bounds__(256) void convert_w(
    const float* __restrict__ Wq, const float* __restrict__ Wk,
    const float* __restrict__ Wv, const float* __restrict__ Wo,
    const float* __restrict__ bq, const float* __restrict__ bk,
    const float* __restrict__ bv, const float* __restrict__ bo,
    unsigned short* __restrict__ W4, float* __restrict__ b4) {
  int i = blockIdx.x * 256 + threadIdx.x;            // 4*512*512 total
  int p = i >> 18, idx = i & 262143;
  const float sc = 1.4426950408889634f * 0.04419417382415922f;  // log2(e) * 512^-0.5
  const float* W = (p == 0) ? Wq : (p == 1) ? Wk : (p == 2) ? Wv : Wo;
  float v = W[idx] * ((p == 0) ? sc : 1.0f);
  W4[i] = f2bf(v);
  if (idx < 512) {
    const float* bb = (p == 0) ? bq : (p == 1) ? bk : (p == 2) ? bv : bo;
    b4[(p << 9) + idx] = bb[idx] * ((p == 0) ? sc : 1.0f);
  }
}

// ---------------- transpose q: fp32 [b][c][s] -> bf16 qT [b][s][c] ----------------
__global__ __launch_bounds__(256) void transpose_q(
    const float* __restrict__ q, unsigned short* __restrict__ qT) {
  __shared__ float tile[32][33];
  const int b = blockIdx.z, c0 = blockIdx.y * 32, s0 = blockIdx.x * 32;
  const int tx = threadIdx.x & 31, ty = threadIdx.x >> 5;
  #pragma unroll
  for (int i = 0; i < 4; i++) {
    int c = ty + i * 8;
    tile[c][tx] = q[((size_t)b * CD + c0 + c) * SEQ + s0 + tx];
  }
  __syncthreads();
  #pragma unroll
  for (int i = 0; i < 4; i++) {
    int s = ty + i * 8;
    qT[((size_t)b * SEQ + s0 + s) * CD + c0 + tx] = f2bf(tile[tx][s]);
  }
}

// ---------------- generalized BT-GEMM core: 128x128 tile, BK=64, 4 waves ----------------
// C[m][n] = sum_k A[m][k] * B[n][k], A rows ld = lda, B rows ld = ldb, K = kmax.
__device__ __forceinline__ void gemm_core2(
    const unsigned short* __restrict__ Ap, size_t lda,
    const unsigned short* __restrict__ Bp, size_t ldb, int kmax,
    unsigned short* As, unsigned short* Bs, f32x4 acc[4][4]) {
  const int t = threadIdx.x;
  const int wid = t >> 6, lane = t & 63;
  const int l15 = lane & 15, l4 = lane >> 4;
  const int wr = wid >> 1, wc = wid & 1;
  for (int k0 = 0; k0 < kmax; k0 += 64) {
    #pragma unroll
    for (int j = 0; j < 4; j++) {
      int slot = j * 256 + t;
      int row = slot >> 3, kc = slot & 7;
      int kcs = kc ^ (row & 7);
      gload_lds16(Ap + (size_t)row * lda + k0 + kcs * 8, As + (j * 256 + wid * 64) * 8);
      gload_lds16(Bp + (size_t)row * ldb + k0 + kcs * 8, Bs + (j * 256 + wid * 64) * 8);
    }
    __syncthreads();
    #pragma unroll
    for (int ks = 0; ks < 2; ks++) {
      bf16x8 af[4], bf[4];
      #pragma unroll
      for (int i = 0; i < 4; i++) {
        int ra = wr * 64 + i * 16 + l15;
        af[i] = *(const bf16x8*)(As + ra * 64 + (((ks << 2) | l4) ^ (ra & 7)) * 8);
        int rb = wc * 64 + i * 16 + l15;
        bf[i] = *(const bf16x8*)(Bs + rb * 64 + (((ks << 2) | l4) ^ (rb & 7)) * 8);
      }
      #pragma unroll
      for (int i = 0; i < 4; i++)
        #pragma unroll
        for (int j = 0; j < 4; j++)
          acc[i][j] = MFMA16(af[i], bf[j], acc[i][j]);
    }
    __syncthreads();
  }
}

__device__ __forceinline__ void gemm_core(
    const unsigned short* __restrict__ Ap, const unsigned short* __restrict__ Bp,
    unsigned short* As, unsigned short* Bs, f32x4 acc[4][4]) {
  gemm_core2(Ap, 512, Bp, 512, 512, As, Bs, acc);
}

// ---------------- QKV projection: z = 0(Q),1(K),2(V transposed) ----------------
__global__ __launch_bounds__(256) void gemm_proj(
    const unsigned short* __restrict__ qT, const unsigned short* __restrict__ W4,
    const float* __restrict__ b4,
    unsigned short* __restrict__ Qf, unsigned short* __restrict__ Kf,
    unsigned short* __restrict__ VfT) {
  __shared__ unsigned short As[128 * 64], Bs[128 * 64];
  const int p = blockIdx.z;
  const int n0 = blockIdx.x * 128, m0 = blockIdx.y * 128;
  f32x4 acc[4][4];
  #pragma unroll
  for (int i = 0; i < 4; i++)
    #pragma unroll
    for (int j = 0; j < 4; j++) acc[i][j] = (f32x4){0.f, 0.f, 0.f, 0.f};
  gemm_core(qT + (size_t)m0 * 512, W4 + ((size_t)p * 512 + n0) * 512, As, Bs, acc);

  const int t = threadIdx.x;
  const int wid = t >> 6, lane = t & 63;
  const int l15 = lane & 15, l4 = lane >> 4;
  const int wr = wid >> 1, wc = wid & 1;

  if (p < 2) {
    unsigned short* out = (p == 0) ? Qf : Kf;
    #pragma unroll
    for (int j = 0; j < 4; j++) {
      int n = n0 + wc * 64 + j * 16 + l15;
      float bias = b4[p * 512 + n];
      #pragma unroll
      for (int i = 0; i < 4; i++) {
        int m = m0 + wr * 64 + i * 16 + l4 * 4;
        #pragma unroll
        for (int r = 0; r < 4; r++)
          out[(size_t)(m + r) * 512 + n] = f2bf(acc[i][j][r] + bias);
      }
    }
  } else {
    int bb = m0 >> 12, sb = m0 & 4095;
    #pragma unroll
    for (int j = 0; j < 4; j++) {
      int n = n0 + wc * 64 + j * 16 + l15;
      float bias = b4[2 * 512 + n];
      #pragma unroll
      for (int i = 0; i < 4; i++) {
        int s = sb + wr * 64 + i * 16 + l4 * 4;
        ushort4 v;
        v.x = f2bf(acc[i][j][0] + bias);
        v.y = f2bf(acc[i][j][1] + bias);
        v.z = f2bf(acc[i][j][2] + bias);
        v.w = f2bf(acc[i][j][3] + bias);
        *(ushort4*)&VfT[((size_t)bb * CD + n) * SEQ + s] = v;
      }
    }
  }
}

// ---------------- QK^T GEMM (SWAPPED: A=K rows k, B=Q rows q) + fused exp2 epilogue ----
// C[k][q]; per lane the 4 register rows are consecutive k -> P[q][k..k+3] ushort4 store.
// P[q][k] = exp2(Q[q]·K[k]) (scale pre-folded, fixed max 0); partials[q][ktile] row sums.
__global__ __launch_bounds__(256) void gemm_qk(
    const unsigned short* __restrict__ Qf, const unsigned short* __restrict__ Kf,
    unsigned short* __restrict__ P, float* __restrict__ partials, int bbase) {
  __shared__ unsigned short As[128 * 64], Bs[128 * 64];
  __shared__ float ssum[2][2][64];
  const int z = blockIdx.z, b = bbase + z;
  const int n0 = blockIdx.x * 128;   // q range
  const int m0 = blockIdx.y * 128;   // k range
  f32x4 acc[4][4];
  #pragma unroll
  for (int i = 0; i < 4; i++)
    #pragma unroll
    for (int j = 0; j < 4; j++) acc[i][j] = (f32x4){0.f, 0.f, 0.f, 0.f};
  gemm_core2(Kf + ((size_t)b * SEQ + m0) * CD, CD,
             Qf + ((size_t)b * SEQ + n0) * CD, CD, CD, As, Bs, acc);

  const int t = threadIdx.x;
  const int wid = t >> 6, lane = t & 63;
  const int l15 = lane & 15, l4 = lane >> 4;
  const int wr = wid >> 1, wc = wid & 1;
  unsigned short* Pz = P + (size_t)z * SEQ * SEQ;

  float sj[4] = {0.f, 0.f, 0.f, 0.f};
  #pragma unroll
  for (int i = 0; i < 4; i++) {
    int m = m0 + wr * 64 + i * 16 + l4 * 4;      // k (4 consecutive in regs)
    #pragma unroll
    for (int j = 0; j < 4; j++) {
      int n = n0 + wc * 64 + j * 16 + l15;       // q
      float p0 = __builtin_amdgcn_exp2f(acc[i][j][0]);
      float p1 = __builtin_amdgcn_exp2f(acc[i][j][1]);
      float p2 = __builtin_amdgcn_exp2f(acc[i][j][2]);
      float p3 = __builtin_amdgcn_exp2f(acc[i][j][3]);
      sj[j] += (p0 + p1) + (p2 + p3);
      ushort4 pk;
      pk.x = f2bf(p0); pk.y = f2bf(p1); pk.z = f2bf(p2); pk.w = f2bf(p3);
      *(ushort4*)&Pz[(size_t)n * SEQ + m] = pk;
    }
  }
  // reduce over l4 groups (lanes sharing the same q differ only in bits 4..5)
  #pragma unroll
  for (int j = 0; j < 4; j++) {
    float s = sj[j];
    s += __shfl_xor(s, 16, 64);
    s += __shfl_xor(s, 32, 64);
    if (lane < 16) ssum[wr][wc][j * 16 + l15] = s;
  }
  __syncthreads();
  if (t < 128) {
    float s = ssum[0][t >> 6][t & 63] + ssum[1][t >> 6][t & 63];
    partials[((size_t)z * SEQ + n0 + t) * 32 + blockIdx.y] = s;
  }
}

// ---------------- l reduce: linv[q] = 1 / sum_32 partials[q][.] ----------------
__global__ __launch_bounds__(256) void reduce_l(
    const float* __restrict__ partials, float* __restrict__ linv) {
  int i = blockIdx.x * 256 + threadIdx.x;
  const float* p = partials + (size_t)i * 32;
  float s = 0.f;
  #pragma unroll
  for (int j = 0; j < 32; j++) s += p[j];
  linv[i] = 1.0f / s;
}

// ---------------- PV GEMM: 128x64 tile (2 blocks/CU): Ao[q][c] = (V·P^T)*linv ----------------
// C[m=c][n=q] = sum_s VfT[c][s] * P[q][s]; grid (q-tiles=64, c-tiles=4, z)
__global__ __launch_bounds__(256) void gemm_pv(
    const unsigned short* __restrict__ VfT, const unsigned short* __restrict__ P,
    const float* __restrict__ linv, unsigned short* __restrict__ Ao, int bbase) {
  __shared__ unsigned short As[128 * 64], Bs[64 * 64];
  const int z = blockIdx.z, b = bbase + z;
  const int n0 = blockIdx.x * 64, m0 = blockIdx.y * 128;
  const int t = threadIdx.x;
  const int wid = t >> 6, lane = t & 63;
  const int l15 = lane & 15, l4 = lane >> 4;
  const int wr = wid >> 1, wc = wid & 1;
  const unsigned short* Ap = VfT + ((size_t)b * CD + m0) * SEQ;
  const unsigned short* Bp = P + (size_t)z * SEQ * SEQ + (size_t)n0 * SEQ;

  f32x4 acc[4][2];
  #pragma unroll
  for (int i = 0; i < 4; i++) {
    acc[i][0] = (f32x4){0.f, 0.f, 0.f, 0.f};
    acc[i][1] = (f32x4){0.f, 0.f, 0.f, 0.f};
  }

  for (int k0 = 0; k0 < SEQ; k0 += 64) {
    #pragma unroll
    for (int j = 0; j < 4; j++) {
      int slot = j * 256 + t;
      int row = slot >> 3, kc = slot & 7;
      int kcs = kc ^ (row & 7);
      gload_lds16(Ap + (size_t)row * SEQ + k0 + kcs * 8, As + (j * 256 + wid * 64) * 8);
    }
    #pragma unroll
    for (int j = 0; j < 2; j++) {
      int slot = j * 256 + t;
      int row = slot >> 3, kc = slot & 7;
      int kcs = kc ^ (row & 7);
      gload_lds16(Bp + (size_t)row * SEQ + k0 + kcs * 8, Bs + (j * 256 + wid * 64) * 8);
    }
    __syncthreads();
    #pragma unroll
    for (int ks = 0; ks < 2; ks++) {
      bf16x8 af[4], bf[2];
      #pragma unroll
      for (int i = 0; i < 4; i++) {
        int ra = wr * 64 + i * 16 + l15;
        af[i] = *(const bf16x8*)(As + ra * 64 + (((ks << 2) | l4) ^ (ra & 7)) * 8);
      }
      #pragma unroll
      for (int j = 0; j < 2; j++) {
        int rb = wc * 32 + j * 16 + l15;
        bf[j] = *(const bf16x8*)(Bs + rb * 64 + (((ks << 2) | l4) ^ (rb & 7)) * 8);
      }
      #pragma unroll
      for (int i = 0; i < 4; i++)
        #pragma unroll
        for (int j = 0; j < 2; j++)
          acc[i][j] = MFMA16(af[i], bf[j], acc[i][j]);
    }
    __syncthreads();
  }

  #pragma unroll
  for (int j = 0; j < 2; j++) {
    int n = n0 + wc * 32 + j * 16 + l15;        // q
    float inv = linv[(size_t)z * SEQ + n];
    #pragma unroll
    for (int i = 0; i < 4; i++) {
      int m = m0 + wr * 64 + i * 16 + l4 * 4;   // c
      ushort4 o4;
      o4.x = f2bf(acc[i][j][0] * inv);
      o4.y = f2bf(acc[i][j][1] * inv);
      o4.z = f2bf(acc[i][j][2] * inv);
      o4.w = f2bf(acc[i][j][3] * inv);
      *(ushort4*)&Ao[((size_t)b * SEQ + n) * CD + m] = o4;
    }
  }
}

// ---------------- flash attention v4 (fallback when workspace is small) ----------------
#define SECTION(T, VRC, VRP, DOPV)                                              \
  {                                                                             \
    const int t_ = (T);                                                         \
    const unsigned short* vt_ = vbase + t_ * 32;                                \
    _Pragma("unroll")                                                           \
    for (int i = 0; i < 8; i++)                                                 \
      VRC[i] = *(const bf16x8*)(vt_ + (size_t)i * 16 * SEQ);                    \
    f32x4 sf = (f32x4){0.f, 0.f, 0.f, 0.f};                                     \
    __builtin_amdgcn_s_setprio(1);                                              \
    {                                                                           \
      const char* krow = (const char*)(Ks + (size_t)(t_ & 3) * 16384) +         \
                         (s * 16 + l15) * 1024;                                 \
      const int kswz = (l15 & 7) << 4;                                          \
      _Pragma("unroll")                                                         \
      for (int ck = 0; ck < 16; ck++) {                                         \
        bf16x8 kf = *(const bf16x8*)(krow + ((ck * 64 + l4 * 16) ^ kswz));      \
        sf = MFMA16(kf, qreg[ck], sf);                                          \
      }                                                                         \
    }                                                                           \
    if (DOPV) {                                                                 \
      _Pragma("unroll")                                                         \
      for (int jf = 0; jf < 2; jf++) {                                          \
        int qv = qw * 32 + jf * 16 + l15;                                       \
        bf16x8 pb = *(const bf16x8*)((const char*)Ps + ((t_ + 1) & 1) * 4096 +  \
                                     qv * 64 +                                  \
                                     ((l4 * 16) ^ (((qv >> 1) & 3) << 4)));     \
        _Pragma("unroll")                                                       \
        for (int i = 0; i < 8; i++)                                             \
          acc[i][jf] = MFMA16(VRP[i], pb, acc[i][jf]);                          \
      }                                                                         \
    }                                                                           \
    __builtin_amdgcn_s_setprio(0);                                              \
    {                                                                           \
      float p0 = __builtin_amdgcn_exp2f(sf[0]);                                 \
      float p1 = __builtin_amdgcn_exp2f(sf[1]);                                 \
      float p2 = __builtin_amdgcn_exp2f(sf[2]);                                 \
      float p3 = __builtin_amdgcn_exp2f(sf[3]);                                 \
      l_acc[0] += p0; l_acc[1] += p1; l_acc[2] += p2; l_acc[3] += p3;           \
      ushort4 pk;                                                               \
      pk.x = f2bf(p0); pk.y = f2bf(p1); pk.z = f2bf(p2); pk.w = f2bf(p3);       \
      int q_ = g * 16 + l15;                                                    \
      int off = (t_ & 1) * 4096 + q_ * 64 +                                     \
                ((s * 32 + l4 * 8) ^ (((q_ >> 1) & 3) << 4));                   \
      *(ushort4*)((char*)Ps + off) = pk;                                        \
    }                                                                           \
    {                                                                           \
      int tt = (t_ + 2 < 128) ? t_ + 2 : 127;                                   \
      const unsigned short* kn = kbT + (size_t)tt * 32 * CD;                    \
      unsigned short* kdst = Ks + (size_t)((t_ + 2) & 3) * 16384;               \
      _Pragma("unroll")                                                         \
      for (int i = 0; i < 4; i++) {                                             \
        int slot = i * 512 + tid;                                               \
        int row = slot >> 6, kc = slot & 63;                                    \
        int kcs = kc ^ (row & 7);                                               \
        gload_lds16(kn + (size_t)row * CD + kcs * 8,                            \
                    kdst + (size_t)(i * 512 + wid * 64) * 8);                   \
      }                                                                         \
    }                                                                           \
    LGKM0;                                                                      \
    VMC12;                                                                      \
    __builtin_amdgcn_s_barrier();                                               \
  }

__global__ __launch_bounds__(512, 2) void flash_attn(
    const unsigned short* __restrict__ Qf, const unsigned short* __restrict__ Kf,
    const unsigned short* __restrict__ VfT, unsigned short* __restrict__ Ao) {
  __shared__ unsigned short Ks[4 * 32 * 512];
  __shared__ unsigned short Ps[2 * 64 * 32];
  __shared__ float ssum[4][2][16];

  const int tid = threadIdx.x;
  const int wid = tid >> 6, lane = tid & 63;
  const int l15 = lane & 15, l4 = lane >> 4;
  const int s = wid & 1, g = wid >> 1;
  const int cw = wid & 3, qw = wid >> 2;

  const int id = blockIdx.x;
  const int xcd = id & 7;
  const int b = xcd >> 1;
  const int q0 = ((id >> 3) + ((xcd & 1) << 5)) * 64;

  const unsigned short* kbT = Kf + (size_t)b * SEQ * CD;
  const unsigned short* vbase = VfT + ((size_t)b * CD + cw * 128 + l15) * SEQ + l4 * 8;

  #pragma unroll
  for (int tt = 0; tt < 2; tt++) {
    const unsigned short* kn = kbT + (size_t)tt * 32 * CD;
    unsigned short* kdst = Ks + (size_t)tt * 16384;
    #pragma unroll
    for (int i = 0; i < 4; i++) {
      int slot = i * 512 + tid;
      int row = slot >> 6, kc = slot & 63;
      int kcs = kc ^ (row & 7);
      gload_lds16(kn + (size_t)row * CD + kcs * 8, kdst + (size_t)(i * 512 + wid * 64) * 8);
    }
  }

  bf16x8 qreg[16];
  {
    const unsigned short* qp = Qf + ((size_t)b * SEQ + q0 + g * 16 + l15) * CD + l4 * 8;
    #pragma unroll
    for (int ck = 0; ck < 16; ck++) qreg[ck] = *(const bf16x8*)(qp + ck * 32);
  }

  f32x4 acc[8][2];
  #pragma unroll
  for (int i = 0; i < 8; i++) {
    acc[i][0] = (f32x4){0.f, 0.f, 0.f, 0.f};
    acc[i][1] = (f32x4){0.f, 0.f, 0.f, 0.f};
  }
  f32x4 l_acc = (f32x4){0.f, 0.f, 0.f, 0.f};

  bf16x8 vrA[8], vrB[8];

  VM0;
  __builtin_amdgcn_s_barrier();

  SECTION(0, vrA, vrB, 0);
  for (int t = 1; t < 127; t += 2) {
    SECTION(t, vrB, vrA, 1);
    SECTION(t + 1, vrA, vrB, 1);
  }
  SECTION(127, vrB, vrA, 1);

  #pragma unroll
  for (int jf = 0; jf < 2; jf++) {
    int qv = qw * 32 + jf * 16 + l15;
    bf16x8 pb = *(const bf16x8*)((const char*)Ps + 4096 + qv * 64 +
                                 ((l4 * 16) ^ (((qv >> 1) & 3) << 4)));
    #pragma unroll
    for (int i = 0; i < 8; i++)
      acc[i][jf] = MFMA16(vrB[i], pb, acc[i][jf]);
  }

  float strip = (l_acc[0] + l_acc[1]) + (l_acc[2] + l_acc[3]);
  strip += __shfl_xor(strip, 16, 64);
  strip += __shfl_xor(strip, 32, 64);
  __syncthreads();
  if (lane < 16) ssum[g][s][l15] = strip;
  __syncthreads();

  #pragma unroll
  for (int jf = 0; jf < 2; jf++) {
    int gq = qw * 2 + jf;
    float inv = 1.0f / (ssum[gq][0][l15] + ssum[gq][1][l15]);
    #pragma unroll
    for (int i = 0; i < 8; i++) {
      int c0 = cw * 128 + i * 16 + l4 * 4;
      ushort4 o4;
      o4.x = f2bf(acc[i][jf][0] * inv);
      o4.y = f2bf(acc[i][jf][1] * inv);
      o4.z = f2bf(acc[i][jf][2] * inv);
      o4.w = f2bf(acc[i][jf][3] * inv);
      *(ushort4*)&Ao[((size_t)b * SEQ + q0 + qw * 32 + jf * 16 + l15) * CD + c0] = o4;
    }
  }
}

// ---------------- output projection: out[b][o][s] fp32 ----------------
__global__ __launch_bounds__(256) void gemm_out(
    const unsigned short* __restrict__ W4, const float* __restrict__ b4,
    const unsigned short* __restrict__ Ao, float* __restrict__ out) {
  __shared__ unsigned short As[128 * 64], Bs[128 * 64];
  const int b = blockIdx.z;
  const int n0 = blockIdx.x * 128, m0 = blockIdx.y * 128;
  f32x4 acc[4][4];
  #pragma unroll
  for (int i = 0; i < 4; i++)
    #pragma unroll
    for (int j = 0; j < 4; j++) acc[i][j] = (f32x4){0.f, 0.f, 0.f, 0.f};
  gemm_core(W4 + ((size_t)3 * 512 + m0) * 512, Ao + ((size_t)b * SEQ + n0) * 512, As, Bs, acc);

  const int t = threadIdx.x;
  const int wid = t >> 6, lane = t & 63;
  const int l15 = lane & 15, l4 = lane >> 4;
  const int wr = wid >> 1, wc = wid & 1;
  #pragma unroll
  for (int i = 0; i < 4; i++) {
    int m = m0 + wr * 64 + i * 16 + l4 * 4;
    #pragma unroll
    for (int j = 0; j < 4; j++) {
      int n = n0 + wc * 64 + j * 16 + l15;
      #pragma unroll
      for (int r = 0; r < 4; r++)
        out[((size_t)b * CD + m + r) * SEQ + n] = acc[i][j][r] + b4[3 * 512 + m + r];
    }
  }
}

extern "C" void kernel_launch(void* const* d_in, const int* in_sizes, int n_in,
                              void* d_out, int out_size, void* d_ws, size_t ws_size,
                              hipStream_t stream) {
  (void)in_sizes; (void)n_in; (void)out_size;
  const float* q  = (const float*)d_in[0];
  const float* Wq = (const float*)d_in[1];
  const float* bq = (const float*)d_in[2];
  const float* Wk = (const float*)d_in[3];
  const float* bk = (const float*)d_in[4];
  const float* Wv = (const float*)d_in[5];
  const float* bv = (const float*)d_in[6];
  const float* Wo = (const float*)d_in[7];
  const float* bo = (const float*)d_in[8];
  float* out = (float*)d_out;

  char* ws = (char*)d_ws;
  const size_t MB = (size_t)1 << 20;
  unsigned short* qT  = (unsigned short*)(ws);            // 16MB (reused as Ao)
  unsigned short* Qf  = (unsigned short*)(ws + 16 * MB);
  unsigned short* Kf  = (unsigned short*)(ws + 32 * MB);
  unsigned short* VfT = (unsigned short*)(ws + 48 * MB);
  unsigned short* W4  = (unsigned short*)(ws + 64 * MB);  // 2MB
  float* b4           = (float*)(ws + 66 * MB);           // 8KB
  unsigned short* Pbuf = (unsigned short*)(ws + 67 * MB); // 32 or 64 MB
  unsigned short* Ao = qT;

  convert_w<<<4096, 256, 0, stream>>>(Wq, Wk, Wv, Wo, bq, bk, bv, bo, W4, b4);
  transpose_q<<<dim3(128, 16, 4), 256, 0, stream>>>(q, qT);
  gemm_proj<<<dim3(4, 128, 3), 256, 0, stream>>>(qT, W4, b4, Qf, Kf, VfT);

  if (ws_size >= 134 * MB) {
    // pair path: P holds 2 batches (64MB), partials at 131MB, linv at 132.5MB
    float* partials = (float*)(ws + 131 * MB);            // 2*4096*32*4 = 1MB
    float* linv     = (float*)(ws + (132 * MB + 512 * 1024));
    for (int pr = 0; pr < 2; ++pr) {
      gemm_qk<<<dim3(32, 32, 2), 256, 0, stream>>>(Qf, Kf, Pbuf, partials, pr * 2);
      reduce_l<<<32, 256, 0, stream>>>(partials, linv);
      gemm_pv<<<dim3(64, 4, 2), 256, 0, stream>>>(VfT, Pbuf, linv, Ao, pr * 2);
    }
  } else if (ws_size >= 101 * MB) {
    // per-batch path: P holds 1 batch (32MB), partials at 99MB, linv at 99.75MB
    float* partials = (float*)(ws + 99 * MB);             // 4096*32*4 = 512KB
    float* linv     = (float*)(ws + (99 * MB + 768 * 1024));
    for (int bb = 0; bb < 4; ++bb) {
      gemm_qk<<<dim3(32, 32, 1), 256, 0, stream>>>(Qf, Kf, Pbuf, partials, bb);
      reduce_l<<<16, 256, 0, stream>>>(partials, linv);
      gemm_pv<<<dim3(64, 4, 1), 256, 0, stream>>>(VfT, Pbuf, linv, Ao, bb);
    }
  } else {
    flash_attn<<<256, 512, 0, stream>>>(Qf, Kf, VfT, Ao);
  }

  gemm_out<<<dim3(32, 4, 4), 256, 0, stream>>>(W4, b4, Ao, out);
}

// Round 9
// 286.763 us; speedup vs baseline: 3.4880x; 1.0440x over previous
//
#include <hip/hip_runtime.h>

typedef short bf16x8 __attribute__((ext_vector_type(8)));
typedef float f32x4 __attribute__((ext_vector_type(4)));

#define MFMA16(a, b, c) __builtin_amdgcn_mfma_f32_16x16x32_bf16((a), (b), (c), 0, 0, 0)

#define SEQ 4096
#define CD 512

#define LGKM0 asm volatile("s_waitcnt lgkmcnt(0)" ::: "memory")
#define VM0   asm volatile("s_waitcnt vmcnt(0)" ::: "memory")
#define VMC12 asm volatile("s_waitcnt vmcnt(12)" ::: "memory")

__device__ __forceinline__ unsigned short f2bf(float f) {
  unsigned u = __builtin_bit_cast(unsigned, f);
  u = u + 0x7FFFu + ((u >> 16) & 1u);
  return (unsigned short)(u >> 16);
}

__device__ __forceinline__ void gload_lds16(const void* g, void* l) {
  __builtin_amdgcn_global_load_lds(
      (const __attribute__((address_space(1))) void*)g,
      (__attribute__((address_space(3))) void*)l, 16, 0, 0);
}

// ---------------- weight convert (fp32 -> bf16, fold softmax scale into Wq/bq) ----------------
__global__ __launch_bounds__(256) void convert_w(
    const float* __restrict__ Wq, const float* __restrict__ Wk,
    const float* __restrict__ Wv, const float* __restrict__ Wo,
    const float* __restrict__ bq, const float* __restrict__ bk,
    const float* __restrict__ bv, const float* __restrict__ bo,
    unsigned short* __restrict__ W4, float* __restrict__ b4) {
  int i = blockIdx.x * 256 + threadIdx.x;            // 4*512*512 total
  int p = i >> 18, idx = i & 262143;
  const float sc = 1.4426950408889634f * 0.04419417382415922f;  // log2(e) * 512^-0.5
  const float* W = (p == 0) ? Wq : (p == 1) ? Wk : (p == 2) ? Wv : Wo;
  float v = W[idx] * ((p == 0) ? sc : 1.0f);
  W4[i] = f2bf(v);
  if (idx < 512) {
    const float* bb = (p == 0) ? bq : (p == 1) ? bk : (p == 2) ? bv : bo;
    b4[(p << 9) + idx] = bb[idx] * ((p == 0) ? sc : 1.0f);
  }
}

// ---------------- transpose q: fp32 [b][c][s] -> bf16 qT [b][s][c] ----------------
__global__ __launch_bounds__(256) void transpose_q(
    const float* __restrict__ q, unsigned short* __restrict__ qT) {
  __shared__ float tile[32][33];
  const int b = blockIdx.z, c0 = blockIdx.y * 32, s0 = blockIdx.x * 32;
  const int tx = threadIdx.x & 31, ty = threadIdx.x >> 5;
  #pragma unroll
  for (int i = 0; i < 4; i++) {
    int c = ty + i * 8;
    tile[c][tx] = q[((size_t)b * CD + c0 + c) * SEQ + s0 + tx];
  }
  __syncthreads();
  #pragma unroll
  for (int i = 0; i < 4; i++) {
    int s = ty + i * 8;
    qT[((size_t)b * SEQ + s0 + s) * CD + c0 + tx] = f2bf(tile[tx][s]);
  }
}

// ---------------- generalized BT-GEMM core: 128x128 tile, BK=64, 4 waves ----------------
__device__ __forceinline__ void gemm_core2(
    const unsigned short* __restrict__ Ap, size_t lda,
    const unsigned short* __restrict__ Bp, size_t ldb, int kmax,
    unsigned short* As, unsigned short* Bs, f32x4 acc[4][4]) {
  const int t = threadIdx.x;
  const int wid = t >> 6, lane = t & 63;
  const int l15 = lane & 15, l4 = lane >> 4;
  const int wr = wid >> 1, wc = wid & 1;
  for (int k0 = 0; k0 < kmax; k0 += 64) {
    #pragma unroll
    for (int j = 0; j < 4; j++) {
      int slot = j * 256 + t;
      int row = slot >> 3, kc = slot & 7;
      int kcs = kc ^ (row & 7);
      gload_lds16(Ap + (size_t)row * lda + k0 + kcs * 8, As + (j * 256 + wid * 64) * 8);
      gload_lds16(Bp + (size_t)row * ldb + k0 + kcs * 8, Bs + (j * 256 + wid * 64) * 8);
    }
    __syncthreads();
    #pragma unroll
    for (int ks = 0; ks < 2; ks++) {
      bf16x8 af[4], bf[4];
      #pragma unroll
      for (int i = 0; i < 4; i++) {
        int ra = wr * 64 + i * 16 + l15;
        af[i] = *(const bf16x8*)(As + ra * 64 + (((ks << 2) | l4) ^ (ra & 7)) * 8);
        int rb = wc * 64 + i * 16 + l15;
        bf[i] = *(const bf16x8*)(Bs + rb * 64 + (((ks << 2) | l4) ^ (rb & 7)) * 8);
      }
      #pragma unroll
      for (int i = 0; i < 4; i++)
        #pragma unroll
        for (int j = 0; j < 4; j++)
          acc[i][j] = MFMA16(af[i], bf[j], acc[i][j]);
    }
    __syncthreads();
  }
}

__device__ __forceinline__ void gemm_core(
    const unsigned short* __restrict__ Ap, const unsigned short* __restrict__ Bp,
    unsigned short* As, unsigned short* Bs, f32x4 acc[4][4]) {
  gemm_core2(Ap, 512, Bp, 512, 512, As, Bs, acc);
}

// ---------------- QKV projection: z = 0(Q),1(K),2(V transposed) ----------------
__global__ __launch_bounds__(256) void gemm_proj(
    const unsigned short* __restrict__ qT, const unsigned short* __restrict__ W4,
    const float* __restrict__ b4,
    unsigned short* __restrict__ Qf, unsigned short* __restrict__ Kf,
    unsigned short* __restrict__ VfT) {
  __shared__ unsigned short As[128 * 64], Bs[128 * 64];
  const int p = blockIdx.z;
  const int n0 = blockIdx.x * 128, m0 = blockIdx.y * 128;
  f32x4 acc[4][4];
  #pragma unroll
  for (int i = 0; i < 4; i++)
    #pragma unroll
    for (int j = 0; j < 4; j++) acc[i][j] = (f32x4){0.f, 0.f, 0.f, 0.f};
  gemm_core(qT + (size_t)m0 * 512, W4 + ((size_t)p * 512 + n0) * 512, As, Bs, acc);

  const int t = threadIdx.x;
  const int wid = t >> 6, lane = t & 63;
  const int l15 = lane & 15, l4 = lane >> 4;
  const int wr = wid >> 1, wc = wid & 1;

  if (p < 2) {
    unsigned short* out = (p == 0) ? Qf : Kf;
    #pragma unroll
    for (int j = 0; j < 4; j++) {
      int n = n0 + wc * 64 + j * 16 + l15;
      float bias = b4[p * 512 + n];
      #pragma unroll
      for (int i = 0; i < 4; i++) {
        int m = m0 + wr * 64 + i * 16 + l4 * 4;
        #pragma unroll
        for (int r = 0; r < 4; r++)
          out[(size_t)(m + r) * 512 + n] = f2bf(acc[i][j][r] + bias);
      }
    }
  } else {
    int bb = m0 >> 12, sb = m0 & 4095;
    #pragma unroll
    for (int j = 0; j < 4; j++) {
      int n = n0 + wc * 64 + j * 16 + l15;
      float bias = b4[2 * 512 + n];
      #pragma unroll
      for (int i = 0; i < 4; i++) {
        int s = sb + wr * 64 + i * 16 + l4 * 4;
        ushort4 v;
        v.x = f2bf(acc[i][j][0] + bias);
        v.y = f2bf(acc[i][j][1] + bias);
        v.z = f2bf(acc[i][j][2] + bias);
        v.w = f2bf(acc[i][j][3] + bias);
        *(ushort4*)&VfT[((size_t)bb * CD + n) * SEQ + s] = v;
      }
    }
  }
}

// ---------------- QK^T 256x256-tile pipelined GEMM + fused exp2 epilogue ----------------
// A = K rows (m=k), B = Q rows (n=q): C[k][q]; P[q][k..k+3] stored as ushort4.
// Double-buffered LDS (128KB), stage-early + single barrier + vmcnt(0)-after-MFMA per K-step.
// 8 waves = 2(wm) x 4(wn); per-wave 128x64 output; acc[8][4].
#define QK_STAGE(BUF, K0)                                                     \
  _Pragma("unroll")                                                           \
  for (int i_ = 0; i_ < 4; i_++) {                                            \
    int slot = i_ * 512 + tid;                                                \
    int row = slot >> 3, kc = slot & 7;                                       \
    int kcs = kc ^ (row & 7);                                                 \
    gload_lds16(Ap + (size_t)row * CD + (K0) + kcs * 8,                       \
                &As[BUF][(i_ * 512 + wid * 64) * 8]);                         \
    gload_lds16(Bp + (size_t)row * CD + (K0) + kcs * 8,                       \
                &Bs[BUF][(i_ * 512 + wid * 64) * 8]);                         \
  }

#define QK_STEP(CUR, NXT, T)                                                  \
  {                                                                           \
    if ((T) < 7) { QK_STAGE(NXT, ((T) + 1) * 64); }                           \
    __builtin_amdgcn_s_setprio(1);                                            \
    _Pragma("unroll")                                                         \
    for (int ks = 0; ks < 2; ks++) {                                          \
      bf16x8 af[8], bf[4];                                                    \
      _Pragma("unroll")                                                       \
      for (int i = 0; i < 8; i++) {                                           \
        int ra = wm * 128 + i * 16 + l15;                                     \
        af[i] = *(const bf16x8*)(&As[CUR][ra * 64 +                           \
                                          ((((ks << 2) | l4) ^ (ra & 7)) * 8)]); \
      }                                                                       \
      _Pragma("unroll")                                                       \
      for (int j = 0; j < 4; j++) {                                           \
        int rb = wn * 64 + j * 16 + l15;                                      \
        bf[j] = *(const bf16x8*)(&Bs[CUR][rb * 64 +                           \
                                          ((((ks << 2) | l4) ^ (rb & 7)) * 8)]); \
      }                                                                       \
      _Pragma("unroll")                                                       \
      for (int i = 0; i < 8; i++)                                             \
        _Pragma("unroll")                                                     \
        for (int j = 0; j < 4; j++)                                           \
          acc[i][j] = MFMA16(af[i], bf[j], acc[i][j]);                        \
    }                                                                         \
    __builtin_amdgcn_s_setprio(0);                                            \
    if ((T) < 7) { VM0; }                                                     \
    __builtin_amdgcn_s_barrier();                                             \
  }

__global__ __launch_bounds__(512, 2) void gemm_qk256(
    const unsigned short* __restrict__ Qf, const unsigned short* __restrict__ Kf,
    unsigned short* __restrict__ P, float* __restrict__ partials,
    int bbase, int nbat) {
  __shared__ unsigned short As[2][256 * 64];   // 64 KB
  __shared__ unsigned short Bs[2][256 * 64];   // 64 KB
  __shared__ float ssum[2][4][4][16];          // [wm][wn][nj][l15]

  const int tid = threadIdx.x;
  const int wid = tid >> 6, lane = tid & 63;
  const int l15 = lane & 15, l4 = lane >> 4;
  const int wm = wid >> 2, wn = wid & 3;

  // XCD-chunked decode: each XCD owns one batch slice + contiguous q-tiles.
  const int id = blockIdx.x;
  const int xcd = id & 7;
  int z, qt, kt;
  if (nbat == 2) {
    z = xcd >> 2;
    int w = id >> 3;                     // 0..63
    qt = ((xcd & 3) << 2) | (w >> 4);    // 16 q-tiles
    kt = w & 15;                         // 16 k-tiles
  } else {
    z = 0;
    int w = id >> 3;                     // 0..31
    qt = (xcd << 1) | (w >> 4);
    kt = w & 15;
  }
  const int b = bbase + z;
  const int m0 = kt * 256;               // k rows
  const int n0 = qt * 256;               // q rows

  const unsigned short* Ap = Kf + ((size_t)b * SEQ + m0) * CD;
  const unsigned short* Bp = Qf + ((size_t)b * SEQ + n0) * CD;

  f32x4 acc[8][4];
  #pragma unroll
  for (int i = 0; i < 8; i++)
    #pragma unroll
    for (int j = 0; j < 4; j++) acc[i][j] = (f32x4){0.f, 0.f, 0.f, 0.f};

  QK_STAGE(0, 0);
  VM0;
  __builtin_amdgcn_s_barrier();

  for (int tt = 0; tt < 4; tt++) {
    QK_STEP(0, 1, tt * 2);
    QK_STEP(1, 0, tt * 2 + 1);
  }

  // ---- epilogue: exp2, store P[q][k] (ushort4), row partial sums ----
  unsigned short* Pz = P + (size_t)z * SEQ * SEQ;
  float sj[4] = {0.f, 0.f, 0.f, 0.f};
  #pragma unroll
  for (int i = 0; i < 8; i++) {
    int m = m0 + wm * 128 + i * 16 + l4 * 4;      // k (4 consecutive)
    #pragma unroll
    for (int j = 0; j < 4; j++) {
      int n = n0 + wn * 64 + j * 16 + l15;        // q
      float p0 = __builtin_amdgcn_exp2f(acc[i][j][0]);
      float p1 = __builtin_amdgcn_exp2f(acc[i][j][1]);
      float p2 = __builtin_amdgcn_exp2f(acc[i][j][2]);
      float p3 = __builtin_amdgcn_exp2f(acc[i][j][3]);
      sj[j] += (p0 + p1) + (p2 + p3);
      ushort4 pk;
      pk.x = f2bf(p0); pk.y = f2bf(p1); pk.z = f2bf(p2); pk.w = f2bf(p3);
      *(ushort4*)&Pz[(size_t)n * SEQ + m] = pk;
    }
  }
  #pragma unroll
  for (int j = 0; j < 4; j++) {
    float s = sj[j];
    s += __shfl_xor(s, 16, 64);
    s += __shfl_xor(s, 32, 64);
    if (lane < 16) ssum[wm][wn][j][l15] = s;
  }
  __syncthreads();
  if (tid < 256) {
    int wn_ = tid >> 6, j_ = (tid >> 4) & 3, l_ = tid & 15;
    float s = ssum[0][wn_][j_][l_] + ssum[1][wn_][j_][l_];
    partials[((size_t)z * SEQ + n0 + tid) * 16 + kt] = s;
  }
}

// ---------------- l reduce: linv[q] = 1 / sum_16 partials[q][.] ----------------
__global__ __launch_bounds__(256) void reduce_l(
    const float* __restrict__ partials, float* __restrict__ linv) {
  int i = blockIdx.x * 256 + threadIdx.x;
  const float* p = partials + (size_t)i * 16;
  float s = 0.f;
  #pragma unroll
  for (int j = 0; j < 16; j++) s += p[j];
  linv[i] = 1.0f / s;
}

// ---------------- PV GEMM: 128x64 tile (2 blocks/CU): Ao[q][c] = (V·P^T)*linv ----------------
__global__ __launch_bounds__(256) void gemm_pv(
    const unsigned short* __restrict__ VfT, const unsigned short* __restrict__ P,
    const float* __restrict__ linv, unsigned short* __restrict__ Ao, int bbase) {
  __shared__ unsigned short As[128 * 64], Bs[64 * 64];
  const int z = blockIdx.z, b = bbase + z;
  const int n0 = blockIdx.x * 64, m0 = blockIdx.y * 128;
  const int t = threadIdx.x;
  const int wid = t >> 6, lane = t & 63;
  const int l15 = lane & 15, l4 = lane >> 4;
  const int wr = wid >> 1, wc = wid & 1;
  const unsigned short* Ap = VfT + ((size_t)b * CD + m0) * SEQ;
  const unsigned short* Bp = P + (size_t)z * SEQ * SEQ + (size_t)n0 * SEQ;

  f32x4 acc[4][2];
  #pragma unroll
  for (int i = 0; i < 4; i++) {
    acc[i][0] = (f32x4){0.f, 0.f, 0.f, 0.f};
    acc[i][1] = (f32x4){0.f, 0.f, 0.f, 0.f};
  }

  for (int k0 = 0; k0 < SEQ; k0 += 64) {
    #pragma unroll
    for (int j = 0; j < 4; j++) {
      int slot = j * 256 + t;
      int row = slot >> 3, kc = slot & 7;
      int kcs = kc ^ (row & 7);
      gload_lds16(Ap + (size_t)row * SEQ + k0 + kcs * 8, As + (j * 256 + wid * 64) * 8);
    }
    #pragma unroll
    for (int j = 0; j < 2; j++) {
      int slot = j * 256 + t;
      int row = slot >> 3, kc = slot & 7;
      int kcs = kc ^ (row & 7);
      gload_lds16(Bp + (size_t)row * SEQ + k0 + kcs * 8, Bs + (j * 256 + wid * 64) * 8);
    }
    __syncthreads();
    #pragma unroll
    for (int ks = 0; ks < 2; ks++) {
      bf16x8 af[4], bf[2];
      #pragma unroll
      for (int i = 0; i < 4; i++) {
        int ra = wr * 64 + i * 16 + l15;
        af[i] = *(const bf16x8*)(As + ra * 64 + (((ks << 2) | l4) ^ (ra & 7)) * 8);
      }
      #pragma unroll
      for (int j = 0; j < 2; j++) {
        int rb = wc * 32 + j * 16 + l15;
        bf[j] = *(const bf16x8*)(Bs + rb * 64 + (((ks << 2) | l4) ^ (rb & 7)) * 8);
      }
      #pragma unroll
      for (int i = 0; i < 4; i++)
        #pragma unroll
        for (int j = 0; j < 2; j++)
          acc[i][j] = MFMA16(af[i], bf[j], acc[i][j]);
    }
    __syncthreads();
  }

  #pragma unroll
  for (int j = 0; j < 2; j++) {
    int n = n0 + wc * 32 + j * 16 + l15;        // q
    float inv = linv[(size_t)z * SEQ + n];
    #pragma unroll
    for (int i = 0; i < 4; i++) {
      int m = m0 + wr * 64 + i * 16 + l4 * 4;   // c
      ushort4 o4;
      o4.x = f2bf(acc[i][j][0] * inv);
      o4.y = f2bf(acc[i][j][1] * inv);
      o4.z = f2bf(acc[i][j][2] * inv);
      o4.w = f2bf(acc[i][j][3] * inv);
      *(ushort4*)&Ao[((size_t)b * SEQ + n) * CD + m] = o4;
    }
  }
}

// ---------------- flash attention v4 (fallback when workspace is small) ----------------
#define SECTION(T, VRC, VRP, DOPV)                                              \
  {                                                                             \
    const int t_ = (T);                                                         \
    const unsigned short* vt_ = vbase + t_ * 32;                                \
    _Pragma("unroll")                                                           \
    for (int i = 0; i < 8; i++)                                                 \
      VRC[i] = *(const bf16x8*)(vt_ + (size_t)i * 16 * SEQ);                    \
    f32x4 sf = (f32x4){0.f, 0.f, 0.f, 0.f};                                     \
    __builtin_amdgcn_s_setprio(1);                                              \
    {                                                                           \
      const char* krow = (const char*)(Ks + (size_t)(t_ & 3) * 16384) +         \
                         (s * 16 + l15) * 1024;                                 \
      const int kswz = (l15 & 7) << 4;                                          \
      _Pragma("unroll")                                                         \
      for (int ck = 0; ck < 16; ck++) {                                         \
        bf16x8 kf = *(const bf16x8*)(krow + ((ck * 64 + l4 * 16) ^ kswz));      \
        sf = MFMA16(kf, qreg[ck], sf);                                          \
      }                                                                         \
    }                                                                           \
    if (DOPV) {                                                                 \
      _Pragma("unroll")                                                         \
      for (int jf = 0; jf < 2; jf++) {                                          \
        int qv = qw * 32 + jf * 16 + l15;                                       \
        bf16x8 pb = *(const bf16x8*)((const char*)Ps + ((t_ + 1) & 1) * 4096 +  \
                                     qv * 64 +                                  \
                                     ((l4 * 16) ^ (((qv >> 1) & 3) << 4)));     \
        _Pragma("unroll")                                                       \
        for (int i = 0; i < 8; i++)                                             \
          acc[i][jf] = MFMA16(VRP[i], pb, acc[i][jf]);                          \
      }                                                                         \
    }                                                                           \
    __builtin_amdgcn_s_setprio(0);                                              \
    {                                                                           \
      float p0 = __builtin_amdgcn_exp2f(sf[0]);                                 \
      float p1 = __builtin_amdgcn_exp2f(sf[1]);                                 \
      float p2 = __builtin_amdgcn_exp2f(sf[2]);                                 \
      float p3 = __builtin_amdgcn_exp2f(sf[3]);                                 \
      l_acc[0] += p0; l_acc[1] += p1; l_acc[2] += p2; l_acc[3] += p3;           \
      ushort4 pk;                                                               \
      pk.x = f2bf(p0); pk.y = f2bf(p1); pk.z = f2bf(p2); pk.w = f2bf(p3);       \
      int q_ = g * 16 + l15;                                                    \
      int off = (t_ & 1) * 4096 + q_ * 64 +                                     \
                ((s * 32 + l4 * 8) ^ (((q_ >> 1) & 3) << 4));                   \
      *(ushort4*)((char*)Ps + off) = pk;                                        \
    }                                                                           \
    {                                                                           \
      int tt = (t_ + 2 < 128) ? t_ + 2 : 127;                                   \
      const unsigned short* kn = kbT + (size_t)tt * 32 * CD;                    \
      unsigned short* kdst = Ks + (size_t)((t_ + 2) & 3) * 16384;               \
      _Pragma("unroll")                                                         \
      for (int i = 0; i < 4; i++) {                                             \
        int slot = i * 512 + tid;                                               \
        int row = slot >> 6, kc = slot & 63;                                    \
        int kcs = kc ^ (row & 7);                                               \
        gload_lds16(kn + (size_t)row * CD + kcs * 8,                            \
                    kdst + (size_t)(i * 512 + wid * 64) * 8);                   \
      }                                                                         \
    }                                                                           \
    LGKM0;                                                                      \
    VMC12;                                                                      \
    __builtin_amdgcn_s_barrier();                                               \
  }

__global__ __launch_bounds__(512, 2) void flash_attn(
    const unsigned short* __restrict__ Qf, const unsigned short* __restrict__ Kf,
    const unsigned short* __restrict__ VfT, unsigned short* __restrict__ Ao) {
  __shared__ unsigned short Ks[4 * 32 * 512];
  __shared__ unsigned short Ps[2 * 64 * 32];
  __shared__ float ssum[4][2][16];

  const int tid = threadIdx.x;
  const int wid = tid >> 6, lane = tid & 63;
  const int l15 = lane & 15, l4 = lane >> 4;
  const int s = wid & 1, g = wid >> 1;
  const int cw = wid & 3, qw = wid >> 2;

  const int id = blockIdx.x;
  const int xcd = id & 7;
  const int b = xcd >> 1;
  const int q0 = ((id >> 3) + ((xcd & 1) << 5)) * 64;

  const unsigned short* kbT = Kf + (size_t)b * SEQ * CD;
  const unsigned short* vbase = VfT + ((size_t)b * CD + cw * 128 + l15) * SEQ + l4 * 8;

  #pragma unroll
  for (int tt = 0; tt < 2; tt++) {
    const unsigned short* kn = kbT + (size_t)tt * 32 * CD;
    unsigned short* kdst = Ks + (size_t)tt * 16384;
    #pragma unroll
    for (int i = 0; i < 4; i++) {
      int slot = i * 512 + tid;
      int row = slot >> 6, kc = slot & 63;
      int kcs = kc ^ (row & 7);
      gload_lds16(kn + (size_t)row * CD + kcs * 8, kdst + (size_t)(i * 512 + wid * 64) * 8);
    }
  }

  bf16x8 qreg[16];
  {
    const unsigned short* qp = Qf + ((size_t)b * SEQ + q0 + g * 16 + l15) * CD + l4 * 8;
    #pragma unroll
    for (int ck = 0; ck < 16; ck++) qreg[ck] = *(const bf16x8*)(qp + ck * 32);
  }

  f32x4 acc[8][2];
  #pragma unroll
  for (int i = 0; i < 8; i++) {
    acc[i][0] = (f32x4){0.f, 0.f, 0.f, 0.f};
    acc[i][1] = (f32x4){0.f, 0.f, 0.f, 0.f};
  }
  f32x4 l_acc = (f32x4){0.f, 0.f, 0.f, 0.f};

  bf16x8 vrA[8], vrB[8];

  VM0;
  __builtin_amdgcn_s_barrier();

  SECTION(0, vrA, vrB, 0);
  for (int t = 1; t < 127; t += 2) {
    SECTION(t, vrB, vrA, 1);
    SECTION(t + 1, vrA, vrB, 1);
  }
  SECTION(127, vrB, vrA, 1);

  #pragma unroll
  for (int jf = 0; jf < 2; jf++) {
    int qv = qw * 32 + jf * 16 + l15;
    bf16x8 pb = *(const bf16x8*)((const char*)Ps + 4096 + qv * 64 +
                                 ((l4 * 16) ^ (((qv >> 1) & 3) << 4)));
    #pragma unroll
    for (int i = 0; i < 8; i++)
      acc[i][jf] = MFMA16(vrB[i], pb, acc[i][jf]);
  }

  float strip = (l_acc[0] + l_acc[1]) + (l_acc[2] + l_acc[3]);
  strip += __shfl_xor(strip, 16, 64);
  strip += __shfl_xor(strip, 32, 64);
  __syncthreads();
  if (lane < 16) ssum[g][s][l15] = strip;
  __syncthreads();

  #pragma unroll
  for (int jf = 0; jf < 2; jf++) {
    int gq = qw * 2 + jf;
    float inv = 1.0f / (ssum[gq][0][l15] + ssum[gq][1][l15]);
    #pragma unroll
    for (int i = 0; i < 8; i++) {
      int c0 = cw * 128 + i * 16 + l4 * 4;
      ushort4 o4;
      o4.x = f2bf(acc[i][jf][0] * inv);
      o4.y = f2bf(acc[i][jf][1] * inv);
      o4.z = f2bf(acc[i][jf][2] * inv);
      o4.w = f2bf(acc[i][jf][3] * inv);
      *(ushort4*)&Ao[((size_t)b * SEQ + q0 + qw * 32 + jf * 16 + l15) * CD + c0] = o4;
    }
  }
}

// ---------------- output projection: out[b][o][s] fp32 ----------------
__global__ __launch_bounds__(256) void gemm_out(
    const unsigned short* __restrict__ W4, const float* __restrict__ b4,
    const unsigned short* __restrict__ Ao, float* __restrict__ out) {
  __shared__ unsigned short As[128 * 64], Bs[128 * 64];
  const int b = blockIdx.z;
  const int n0 = blockIdx.x * 128, m0 = blockIdx.y * 128;
  f32x4 acc[4][4];
  #pragma unroll
  for (int i = 0; i < 4; i++)
    #pragma unroll
    for (int j = 0; j < 4; j++) acc[i][j] = (f32x4){0.f, 0.f, 0.f, 0.f};
  gemm_core(W4 + ((size_t)3 * 512 + m0) * 512, Ao + ((size_t)b * SEQ + n0) * 512, As, Bs, acc);

  const int t = threadIdx.x;
  const int wid = t >> 6, lane = t & 63;
  const int l15 = lane & 15, l4 = lane >> 4;
  const int wr = wid >> 1, wc = wid & 1;
  #pragma unroll
  for (int i = 0; i < 4; i++) {
    int m = m0 + wr * 64 + i * 16 + l4 * 4;
    #pragma unroll
    for (int j = 0; j < 4; j++) {
      int n = n0 + wc * 64 + j * 16 + l15;
      #pragma unroll
      for (int r = 0; r < 4; r++)
        out[((size_t)b * CD + m + r) * SEQ + n] = acc[i][j][r] + b4[3 * 512 + m + r];
    }
  }
}

extern "C" void kernel_launch(void* const* d_in, const int* in_sizes, int n_in,
                              void* d_out, int out_size, void* d_ws, size_t ws_size,
                              hipStream_t stream) {
  (void)in_sizes; (void)n_in; (void)out_size;
  const float* q  = (const float*)d_in[0];
  const float* Wq = (const float*)d_in[1];
  const float* bq = (const float*)d_in[2];
  const float* Wk = (const float*)d_in[3];
  const float* bk = (const float*)d_in[4];
  const float* Wv = (const float*)d_in[5];
  const float* bv = (const float*)d_in[6];
  const float* Wo = (const float*)d_in[7];
  const float* bo = (const float*)d_in[8];
  float* out = (float*)d_out;

  char* ws = (char*)d_ws;
  const size_t MB = (size_t)1 << 20;
  unsigned short* qT  = (unsigned short*)(ws);            // 16MB (reused as Ao)
  unsigned short* Qf  = (unsigned short*)(ws + 16 * MB);
  unsigned short* Kf  = (unsigned short*)(ws + 32 * MB);
  unsigned short* VfT = (unsigned short*)(ws + 48 * MB);
  unsigned short* W4  = (unsigned short*)(ws + 64 * MB);  // 2MB
  float* b4           = (float*)(ws + 66 * MB);           // 8KB
  unsigned short* Pbuf = (unsigned short*)(ws + 67 * MB); // 32 or 64 MB
  unsigned short* Ao = qT;

  convert_w<<<4096, 256, 0, stream>>>(Wq, Wk, Wv, Wo, bq, bk, bv, bo, W4, b4);
  transpose_q<<<dim3(128, 16, 4), 256, 0, stream>>>(q, qT);
  gemm_proj<<<dim3(4, 128, 3), 256, 0, stream>>>(qT, W4, b4, Qf, Kf, VfT);

  if (ws_size >= 134 * MB) {
    // pair path: P holds 2 batches (64MB), partials at 131MB, linv at 132.5MB
    float* partials = (float*)(ws + 131 * MB);            // 2*4096*16*4 = 512KB
    float* linv     = (float*)(ws + (132 * MB + 512 * 1024));
    for (int pr = 0; pr < 2; ++pr) {
      gemm_qk256<<<512, 512, 0, stream>>>(Qf, Kf, Pbuf, partials, pr * 2, 2);
      reduce_l<<<32, 256, 0, stream>>>(partials, linv);
      gemm_pv<<<dim3(64, 4, 2), 256, 0, stream>>>(VfT, Pbuf, linv, Ao, pr * 2);
    }
  } else if (ws_size >= 101 * MB) {
    // per-batch path: P holds 1 batch (32MB), partials at 99MB, linv at 99.75MB
    float* partials = (float*)(ws + 99 * MB);             // 4096*16*4 = 256KB
    float* linv     = (float*)(ws + (99 * MB + 768 * 1024));
    for (int bb = 0; bb < 4; ++bb) {
      gemm_qk256<<<256, 512, 0, stream>>>(Qf, Kf, Pbuf, partials, bb, 1);
      reduce_l<<<16, 256, 0, stream>>>(partials, linv);
      gemm_pv<<<dim3(64, 4, 1), 256, 0, stream>>>(VfT, Pbuf, linv, Ao, bb);
    }
  } else {
    flash_attn<<<256, 512, 0, stream>>>(Qf, Kf, VfT, Ao);
  }

  gemm_out<<<dim3(32, 4, 4), 256, 0, stream>>>(W4, b4, Ao, out);
}